// Round 4
// baseline (386.621 us; speedup 1.0000x reference)
//
#include <hip/hip_runtime.h>
#include <cstdint>
#include <cstddef>

typedef __attribute__((ext_vector_type(4))) float v4f;
typedef __attribute__((ext_vector_type(8))) short v8s;
typedef __attribute__((ext_vector_type(4))) short v4s;

__device__ __forceinline__ short f2bf(float f) {
  unsigned u = __float_as_uint(f);
  u += 0x7FFFu + ((u >> 16) & 1u);   // round-to-nearest-even
  return (short)(u >> 16);
}
__device__ __forceinline__ float bf2f(short h) {
  return __uint_as_float(((unsigned)(unsigned short)h) << 16);
}
__device__ __forceinline__ v4f mfma16(v8s a, v8s b, v4f c) {
  return __builtin_amdgcn_mfma_f32_16x16x32_bf16(a, b, c, 0, 0, 0);
}
// word-index swizzle for [64][128] fp32 staging: 2-way max write conflict, aligned 16B reads
__device__ __forceinline__ int swzw(int row, int colw) {
  return (row * 128 + colw) ^ ((row & 7) << 2);
}

// ---------------- workspace layout (bytes) ----------------
#define OFF_GRAM   0u          // double[2*8*16*16] = 32768
#define OFF_QN     32768u      // double[256]
#define OFF_KN     34816u      // double[256]
#define OFF_GSUM   36864u      // double[1]
#define OFF_ATTN   40960u      // float[4096]
#define OFF_WQH    65536u      // short[384*128]
#define OFF_WQL    163840u
#define OFF_G1H    262144u     // short[128*256]
#define OFF_G1L    327680u
#define OFF_W2     393216u     // short[2*256*256]
#define OFF_QK     1048576u    // float[131072*256] pixel-major (q ch 0..127, k ch 128..255)
#define OFF_V      135266304u  // short[131072*128] pixel-major bf16 (raw v)
#define OFF_VOUT   168820736u  // short[131072*128] post-conv v
// total ~193 MiB

// K0: split fp32 weights into bf16 hi/lo planes (for fp32-accurate split MFMA)
__global__ void k0_split(const float* __restrict__ qkv_w, const float* __restrict__ g1_w,
                         short* __restrict__ wqh, short* __restrict__ wql,
                         short* __restrict__ g1h, short* __restrict__ g1l) {
  int i = blockIdx.x * 256 + threadIdx.x;
  if (i < 49152) {
    float f = qkv_w[i]; short h = f2bf(f);
    wqh[i] = h; wql[i] = f2bf(f - bf2f(h));
  }
  int j = i - 49152;
  if (j >= 0 && j < 32768) {
    float f = g1_w[j]; short h = f2bf(f);
    g1h[j] = h; g1l[j] = f2bf(f - bf2f(h));
  }
}

// K1: qkv = x1 @ Wqkv^T  (M=131072, K=128, N=384).
// A staged once to LDS (hi/lo) -> registers; B streamed global->reg (L2-hot).
// q,k: 3-term split-bf16, fp32 out via LDS-transposed COALESCED stores. v: 1-term, bf16.
__global__ __launch_bounds__(512) void k1_qkv(const float* __restrict__ x,
                                              const short* __restrict__ wqh,
                                              const short* __restrict__ wql,
                                              float* __restrict__ qkf,
                                              short* __restrict__ vb) {
  __shared__ __align__(16) unsigned char sm[49152]; // Ah@0 Al@16384 (later: fp32 store-staging @0); vtr@32768
  const int tid = threadIdx.x;
  const size_t m0 = (size_t)blockIdx.x * 64;
  { // stage A = x rows, cols 0..127, converted to hi/lo bf16
    const int row = tid >> 3, c0 = (tid & 7) * 16;
    const float* src = x + (m0 + (size_t)row) * 256 + c0;
#pragma unroll
    for (int half = 0; half < 2; ++half) {
      v4f f0 = *(const v4f*)(src + half * 8);
      v4f f1 = *(const v4f*)(src + half * 8 + 4);
      v8s hi, lo;
#pragma unroll
      for (int j = 0; j < 4; ++j) {
        short h0 = f2bf(f0[j]); hi[j] = h0;   lo[j]   = f2bf(f0[j] - bf2f(h0));
        short h1 = f2bf(f1[j]); hi[4+j] = h1; lo[4+j] = f2bf(f1[j] - bf2f(h1));
      }
      const int col = c0 + half * 8;
      const int byo = (row * 256 + col * 2) ^ ((row & 7) << 4);
      *(v8s*)(sm + byo) = hi;
      *(v8s*)(sm + 16384 + byo) = lo;
    }
  }
  __syncthreads();
  const int lane = tid & 63, wid = tid >> 6;
  const int wm = wid >> 2, wn = wid & 3; // 2(m) x 4(n) waves
  // A fragments -> registers (reused across all 6 n-chunks)
  v8s ah[4][2], al[4][2];
#pragma unroll
  for (int ks = 0; ks < 4; ++ks)
#pragma unroll
    for (int mi = 0; mi < 2; ++mi) {
      const int kb2 = (ks * 32 + ((lane >> 4) * 8)) * 2;
      const int m = wm * 32 + mi * 16 + (lane & 15);
      const int byoA = (m * 256 + kb2) ^ ((m & 7) << 4);
      ah[ks][mi] = *(const v8s*)(sm + byoA);
      al[ks][mi] = *(const v8s*)(sm + 16384 + byoA);
    }
  const v4f vz = {0.f, 0.f, 0.f, 0.f};
  v4f acc[6][2];
#pragma unroll
  for (int i = 0; i < 6; ++i) { acc[i][0] = vz; acc[i][1] = vz; }
  const int nrow = wn * 16 + (lane & 15);
  const int kcol = (lane >> 4) * 8;
#pragma unroll
  for (int nc = 0; nc < 6; ++nc) {
#pragma unroll
    for (int ks = 0; ks < 4; ++ks) {
      const size_t boff = (size_t)(nc * 64 + nrow) * 128 + ks * 32 + kcol;
      const v8s bh = *(const v8s*)(wqh + boff);
      if (nc < 4) {
        const v8s bl = *(const v8s*)(wql + boff);
#pragma unroll
        for (int mi = 0; mi < 2; ++mi) {
          acc[nc][mi] = mfma16(ah[ks][mi], bh, acc[nc][mi]);
          acc[nc][mi] = mfma16(al[ks][mi], bh, acc[nc][mi]);
          acc[nc][mi] = mfma16(ah[ks][mi], bl, acc[nc][mi]);
        }
      } else {
#pragma unroll
        for (int mi = 0; mi < 2; ++mi)
          acc[nc][mi] = mfma16(ah[ks][mi], bh, acc[nc][mi]);
      }
    }
  }
  // epilogue: q,k fp32 via LDS transpose -> fully coalesced 1KB/wave stores
  float* st = (float*)sm;   // [64][128] fp32 staging, swizzled; A region is dead
#pragma unroll
  for (int ch = 0; ch < 2; ++ch) {
    __syncthreads();
#pragma unroll
    for (int nci = 0; nci < 2; ++nci)
#pragma unroll
      for (int mi = 0; mi < 2; ++mi)
#pragma unroll
        for (int r = 0; r < 4; ++r) {
          const int m = wm * 32 + mi * 16 + ((lane >> 4) * 4) + r;
          const int cw = nci * 64 + wn * 16 + (lane & 15);
          st[swzw(m, cw)] = acc[ch * 2 + nci][mi][r];
        }
    __syncthreads();
    const int base = tid * 4;
#pragma unroll
    for (int p = 0; p < 4; ++p) {
      const int flat = p * 2048 + base;
      const int row = flat >> 7, colw = flat & 127;
      const v4f t = *(const v4f*)(st + swzw(row, colw));
      *(v4f*)(qkf + (m0 + row) * 256 + ch * 128 + colw) = t;
    }
  }
  // v -> bf16 via LDS transpose, coalesced 16B stores
  short* vtr = (short*)(sm + 32768);
#pragma unroll
  for (int nc = 4; nc < 6; ++nc)
#pragma unroll
    for (int mi = 0; mi < 2; ++mi)
#pragma unroll
      for (int r = 0; r < 4; ++r) {
        const int m = wm * 32 + mi * 16 + ((lane >> 4) * 4) + r;
        const int n = (nc - 4) * 64 + wn * 16 + (lane & 15);
        vtr[m * 128 + n] = f2bf(acc[nc][mi][r]);
      }
  __syncthreads();
  {
    const int base = tid * 8;   // shorts
#pragma unroll
    for (int p = 0; p < 2; ++p) {
      const int flat = p * 4096 + base;
      const int row = flat >> 7, col = flat & 127;
      const v8s t = *(const v8s*)(vtr + row * 128 + col);
      *(v8s*)(vb + (m0 + row) * 128 + col) = t;
    }
  }
}

// K1g: g1 = x @ W1^T (K=256,N=128) split-bf16 4-term, B streamed global->reg;
// fused relu+g2 dot+sigmoid+global mean (double atomic)
__global__ __launch_bounds__(512) void k1_g(const float* __restrict__ x,
                                            const short* __restrict__ g1h,
                                            const short* __restrict__ g1l,
                                            const float* __restrict__ g1_b,
                                            const float* __restrict__ g2_w,
                                            const float* __restrict__ g2_b,
                                            double* __restrict__ gsum) {
  __shared__ __align__(16) unsigned char sm[32768]; // Ah@0 Al@16384
  const int tid = threadIdx.x;
  const size_t m0 = (size_t)blockIdx.x * 64;
  const int lane = tid & 63, wid = tid >> 6;
  const int wm = wid >> 2, wn = wid & 3;
  const v4f vz = {0.f, 0.f, 0.f, 0.f};
  v4f acc[2][2];
  acc[0][0] = vz; acc[0][1] = vz; acc[1][0] = vz; acc[1][1] = vz;
  const int nrow = wn * 16 + (lane & 15);
  const int kcol = (lane >> 4) * 8;
#pragma unroll
  for (int kc = 0; kc < 2; ++kc) {
    __syncthreads();
    { // stage A chunk (cols kc*128..+128) hi/lo
      const int row = tid >> 3, c0 = (tid & 7) * 16;
      const float* src = x + (m0 + (size_t)row) * 256 + kc * 128 + c0;
#pragma unroll
      for (int half = 0; half < 2; ++half) {
        v4f f0 = *(const v4f*)(src + half * 8);
        v4f f1 = *(const v4f*)(src + half * 8 + 4);
        v8s hi, lo;
#pragma unroll
        for (int j = 0; j < 4; ++j) {
          short h0 = f2bf(f0[j]); hi[j] = h0;   lo[j]   = f2bf(f0[j] - bf2f(h0));
          short h1 = f2bf(f1[j]); hi[4+j] = h1; lo[4+j] = f2bf(f1[j] - bf2f(h1));
        }
        const int col = c0 + half * 8;
        const int byo = (row * 256 + col * 2) ^ ((row & 7) << 4);
        *(v8s*)(sm + byo) = hi;
        *(v8s*)(sm + 16384 + byo) = lo;
      }
    }
    __syncthreads();
    v8s ah[4][2], al[4][2];
#pragma unroll
    for (int ks = 0; ks < 4; ++ks)
#pragma unroll
      for (int mi = 0; mi < 2; ++mi) {
        const int kb2 = (ks * 32 + ((lane >> 4) * 8)) * 2;
        const int m = wm * 32 + mi * 16 + (lane & 15);
        const int byoA = (m * 256 + kb2) ^ ((m & 7) << 4);
        ah[ks][mi] = *(const v8s*)(sm + byoA);
        al[ks][mi] = *(const v8s*)(sm + 16384 + byoA);
      }
#pragma unroll
    for (int nc = 0; nc < 2; ++nc) {
#pragma unroll
      for (int ks = 0; ks < 4; ++ks) {
        const size_t boff = (size_t)(nc * 64 + nrow) * 256 + kc * 128 + ks * 32 + kcol;
        const v8s bh = *(const v8s*)(g1h + boff);
        const v8s bl = *(const v8s*)(g1l + boff);
#pragma unroll
        for (int mi = 0; mi < 2; ++mi) {
          acc[nc][mi] = mfma16(ah[ks][mi], bh, acc[nc][mi]);
          acc[nc][mi] = mfma16(al[ks][mi], bh, acc[nc][mi]);
          acc[nc][mi] = mfma16(ah[ks][mi], bl, acc[nc][mi]);
          acc[nc][mi] = mfma16(al[ks][mi], bl, acc[nc][mi]);
        }
      }
    }
  }
  // epilogue: per-pixel g2 dot + sigmoid + block sum -> double atomic
  __syncthreads();
  float* g2ws = (float*)sm;           // aliases dead A region
  float* ldsg = (float*)(sm + 512);
  if (tid < 128) g2ws[tid] = g2_w[tid];
  if (tid < 64) ldsg[tid] = 0.f;
  __syncthreads();
  float bias[2], g2v[2];
#pragma unroll
  for (int nc = 0; nc < 2; ++nc) {
    const int n = nc * 64 + wn * 16 + (lane & 15);
    bias[nc] = g1_b[n];
    g2v[nc] = g2ws[n];
  }
#pragma unroll
  for (int mi = 0; mi < 2; ++mi)
#pragma unroll
    for (int r = 0; r < 4; ++r) {
      float part = 0.f;
#pragma unroll
      for (int nc = 0; nc < 2; ++nc) {
        float val = acc[nc][mi][r] + bias[nc];
        val = fmaxf(val, 0.f);
        part += val * g2v[nc];
      }
      part += __shfl_xor(part, 1, 16);
      part += __shfl_xor(part, 2, 16);
      part += __shfl_xor(part, 4, 16);
      part += __shfl_xor(part, 8, 16);
      if ((lane & 15) == 0)
        atomicAdd(&ldsg[wm * 32 + mi * 16 + ((lane >> 4) * 4) + r], part);
    }
  __syncthreads();
  if (tid < 64) {
    float pre = ldsg[tid] + g2_b[0];
    float g = 1.f / (1.f + expf(-pre));
#pragma unroll
    for (int mk = 1; mk < 64; mk <<= 1) g += __shfl_xor(g, mk, 64);
    if (tid == 0) atomicAdd(gsum, (double)g);
  }
}

// K2: thread = (channel, row). Fused dwconv + norms + gram + v write.
__global__ __launch_bounds__(256, 4) void k2_conv(const float* __restrict__ qkf,
                                                  const short* __restrict__ vb,
                                                  const float* __restrict__ dw_w,
                                                  double* __restrict__ gram,
                                                  double* __restrict__ qn,
                                                  double* __restrict__ kn,
                                                  short* __restrict__ vbuf) {
  __shared__ __align__(16) unsigned char SM[25984];
  float* haloT = (float*)SM;                 // [c][325]: plane c, elem hy*18+hx
  short* vtr   = (short*)SM;                 // alias, [px][24]
  float* wsm   = (float*)(SM + 20800);       // [16][9]
  float* redQ  = (float*)(SM + 21376);       // [wave][16]
  float* redK  = (float*)(SM + 21632);
  float* gramW = (float*)(SM + 21888);       // [wave][256]

  const int tid = threadIdx.x;
  const int tile = blockIdx.x, h = blockIdx.y, b = blockIdx.z;
  const int px0 = (tile & 15) * 16, py0 = (tile >> 4) * 16;
  const int c = tid & 15, r = tid >> 4;
  const int lane = tid & 63, w4 = tid >> 6;

  auto stage = [&](int sec) {
    const int chbase = sec * 128 + h * 16;
#pragma unroll
    for (int i = 0; i < 6; ++i) {
      const int idx = tid + i * 256;
      if (idx < 1296) {
        const int p = idx >> 2, e4 = (idx & 3) * 4;
        const int row = p / 18, col = p - row * 18;
        const int gy = py0 - 1 + row, gx = px0 - 1 + col;
        v4f val = {0.f, 0.f, 0.f, 0.f};
        if (gy >= 0 && gy < 256 && gx >= 0 && gx < 256) {
          const size_t pix = (size_t)(b * 65536 + gy * 256 + gx);
          if (sec < 2) {
            val = *(const v4f*)(qkf + pix * 256 + sec * 128 + h * 16 + e4);
          } else {
            const v4s sv = *(const v4s*)(vb + pix * 128 + h * 16 + e4);
            val[0] = bf2f(sv[0]); val[1] = bf2f(sv[1]);
            val[2] = bf2f(sv[2]); val[3] = bf2f(sv[3]);
          }
        }
        haloT[(e4 + 0) * 325 + p] = val[0];
        haloT[(e4 + 1) * 325 + p] = val[1];
        haloT[(e4 + 2) * 325 + p] = val[2];
        haloT[(e4 + 3) * 325 + p] = val[3];
      }
    }
    if (tid < 144) wsm[tid] = dw_w[chbase * 9 + tid];
  };

  auto conv16 = [&](float* o) {
#pragma unroll
    for (int j = 0; j < 16; ++j) o[j] = 0.f;
#pragma unroll
    for (int dy = 0; dy < 3; ++dy) {
      const float* rp = haloT + c * 325 + (r + dy) * 18;
      float rowb[18];
#pragma unroll
      for (int xx = 0; xx < 18; ++xx) rowb[xx] = rp[xx];
      const float w0 = wsm[c * 9 + dy * 3 + 0];
      const float w1 = wsm[c * 9 + dy * 3 + 1];
      const float w2 = wsm[c * 9 + dy * 3 + 2];
#pragma unroll
      for (int j = 0; j < 16; ++j)
        o[j] += w0 * rowb[j] + w1 * rowb[j + 1] + w2 * rowb[j + 2];
    }
  };

  float qreg[16], kreg[16];

  stage(0);
  __syncthreads();
  conv16(qreg);
  {
    float s = 0.f;
#pragma unroll
    for (int j = 0; j < 16; ++j) s += qreg[j] * qreg[j];
    s += __shfl_xor(s, 16, 64);
    s += __shfl_xor(s, 32, 64);
    if (lane < 16) redQ[w4 * 16 + lane] = s;
  }
  __syncthreads();
  stage(1);
  __syncthreads();
  conv16(kreg);
  {
    float s = 0.f;
#pragma unroll
    for (int j = 0; j < 16; ++j) s += kreg[j] * kreg[j];
    s += __shfl_xor(s, 16, 64);
    s += __shfl_xor(s, 32, 64);
    if (lane < 16) redK[w4 * 16 + lane] = s;
  }
  { // gram: wave covers px [64*w4, 64*w4+64); split-bf16 MFMA
    v4f acc = {0.f, 0.f, 0.f, 0.f};
    const int qt = lane >> 4;
    const bool hiHalf = (qt & 1);
#pragma unroll
    for (int f = 0; f < 2; ++f) {
      const int src = ((f * 2 + (qt >> 1)) << 4) | (lane & 15);
      v8s qh, ql, kh, kl;
#pragma unroll
      for (int j = 0; j < 8; ++j) {
        const float qa = __shfl(qreg[j], src, 64);
        const float qb = __shfl(qreg[j + 8], src, 64);
        const float ka = __shfl(kreg[j], src, 64);
        const float kb = __shfl(kreg[j + 8], src, 64);
        const float qv = hiHalf ? qb : qa;
        const float kv = hiHalf ? kb : ka;
        const short h1 = f2bf(qv); qh[j] = h1; ql[j] = f2bf(qv - bf2f(h1));
        const short h2 = f2bf(kv); kh[j] = h2; kl[j] = f2bf(kv - bf2f(h2));
      }
      acc = mfma16(qh, kh, acc);
      acc = mfma16(ql, kh, acc);
      acc = mfma16(qh, kl, acc);
      acc = mfma16(ql, kl, acc);
    }
#pragma unroll
    for (int rr = 0; rr < 4; ++rr)
      gramW[w4 * 256 + (qt * 4 + rr) * 16 + (lane & 15)] = acc[rr];
  }
  __syncthreads();
  stage(2);
  __syncthreads();
  float vv[16];
  conv16(vv);
  if (tid < 16) {
    const float t = redQ[tid] + redQ[16 + tid] + redQ[32 + tid] + redQ[48 + tid];
    atomicAdd(&qn[b * 128 + h * 16 + tid], (double)t);
  } else if (tid < 32) {
    const int cc = tid - 16;
    const float t = redK[cc] + redK[16 + cc] + redK[32 + cc] + redK[48 + cc];
    atomicAdd(&kn[b * 128 + h * 16 + cc], (double)t);
  }
  {
    const float g = gramW[tid] + gramW[256 + tid] + gramW[512 + tid] + gramW[768 + tid];
    atomicAdd(&gram[(size_t)(b * 8 + h) * 256 + tid], (double)g);
  }
  __syncthreads();
  {
#pragma unroll
    for (int j = 0; j < 16; ++j) vtr[(r * 16 + j) * 24 + c] = f2bf(vv[j]);
  }
  __syncthreads();
  {
    const v8s o0 = *(const v8s*)(vtr + tid * 24);
    const v8s o1 = *(const v8s*)(vtr + tid * 24 + 8);
    short* dst = vbuf + ((size_t)b * 65536 + (size_t)(py0 + (tid >> 4)) * 256 + (px0 + (tid & 15))) * 128 + h * 16;
    *(v8s*)dst = o0;
    *(v8s*)(dst + 8) = o1;
  }
}

// K3a: normalize gram -> cosine attn, temperature, dyn_k top-k mask, softmax, *sum(attn1..4)
__global__ void k3a_attn(const double* __restrict__ gram, const double* __restrict__ qn,
                         const double* __restrict__ kn, const double* __restrict__ gsum,
                         const float* __restrict__ temp,
                         const float* __restrict__ a1p, const float* __restrict__ a2p,
                         const float* __restrict__ a3p, const float* __restrict__ a4p,
                         float* __restrict__ attnw) {
  const int t = threadIdx.x;  // 256 rows: (b,h,c)
  const int b = t >> 7, rem = t & 127, h = rem >> 4, c = rem & 15;
  const float qnv = fmaxf(sqrtf((float)qn[b * 128 + h * 16 + c]), 1e-12f);
  const float tv = temp[h];
  float a[16];
#pragma unroll
  for (int d = 0; d < 16; ++d) {
    const float knv = fmaxf(sqrtf((float)kn[b * 128 + h * 16 + d]), 1e-12f);
    a[d] = (float)gram[(size_t)(b * 8 + h) * 256 + c * 16 + d] / (qnv * knv) * tv;
  }
  const float dynk = floorf(16.f * (float)(gsum[0] / 131072.0));
  float mx = -INFINITY;
  bool keep[16];
#pragma unroll
  for (int d = 0; d < 16; ++d) {
    int rank = 0;
#pragma unroll
    for (int e = 0; e < 16; ++e)
      rank += ((a[e] > a[d]) || ((a[e] == a[d]) && (e < d))) ? 1 : 0;
    keep[d] = ((float)rank < dynk);
    if (keep[d]) mx = fmaxf(mx, a[d]);
  }
  float ssum = 0.f, wvv[16];
#pragma unroll
  for (int d = 0; d < 16; ++d) {
    wvv[d] = keep[d] ? expf(a[d] - mx) : 0.f;
    ssum += wvv[d];
  }
  const float satt = a1p[0] + a2p[0] + a3p[0] + a4p[0];
  const float sc = satt / ssum;
#pragma unroll
  for (int d = 0; d < 16; ++d) attnw[t * 16 + d] = wvv[d] * sc;
}

// K3b: fold attention into projection: W2[b][o][c'] (bf16)
__global__ void k3b_fold(const float* __restrict__ proj_w, const float* __restrict__ attnw,
                         short* __restrict__ W2) {
  const int o = blockIdx.x, b = blockIdx.y, cp = threadIdx.x;  // 256 threads
  float val;
  if (cp < 128) {
    const int h = cp >> 4, d = cp & 15;
    float s = 0.f;
#pragma unroll
    for (int i = 0; i < 16; ++i)
      s += proj_w[o * 256 + h * 16 + i] * attnw[((b * 8 + h) * 16 + i) * 16 + d];
    val = s;
  } else {
    val = proj_w[o * 256 + cp];
  }
  W2[(size_t)(b * 256 + o) * 256 + cp] = f2bf(val);
}

// K4: out[m][o] = [v(m) ; x2(m)] @ W2[b]^T   (M=131072, K=256, N=256) plain bf16 MFMA.
// Epilogue via LDS transpose -> fully coalesced stores.
__global__ __launch_bounds__(512) void k4_out(const short* __restrict__ vbuf,
                                              const float* __restrict__ x,
                                              const short* __restrict__ W2,
                                              float* __restrict__ out) {
  __shared__ __align__(16) unsigned char sm[65536]; // A [64][256] bf16 @0, B [64][256] bf16 @32768
  const int tid = threadIdx.x;
  const size_t m0 = (size_t)blockIdx.x * 64;
  const int b = (int)(m0 >> 16);
  {
    const int row = tid >> 3, c0 = (tid & 7) * 16;
    { // cols 0..127 from v (already bf16)
      const short* src = vbuf + (m0 + (size_t)row) * 128 + c0;
#pragma unroll
      for (int half = 0; half < 2; ++half) {
        const int col = c0 + half * 8;
        const int byo = (row * 512 + col * 2) ^ ((row & 7) << 4);
        *(v8s*)(sm + byo) = *(const v8s*)(src + half * 8);
      }
    }
    { // cols 128..255 from x2 (fp32 -> bf16)
      const float* src = x + (m0 + (size_t)row) * 256 + 128 + c0;
#pragma unroll
      for (int half = 0; half < 2; ++half) {
        v4f f0 = *(const v4f*)(src + half * 8);
        v4f f1 = *(const v4f*)(src + half * 8 + 4);
        v8s hv;
#pragma unroll
        for (int j = 0; j < 4; ++j) { hv[j] = f2bf(f0[j]); hv[4+j] = f2bf(f1[j]); }
        const int col = 128 + c0 + half * 8;
        const int byo = (row * 512 + col * 2) ^ ((row & 7) << 4);
        *(v8s*)(sm + byo) = hv;
      }
    }
  }
  const int lane = tid & 63, wid = tid >> 6;
  const int wm = wid >> 2, wn = wid & 3;
  const v4f vz = {0.f, 0.f, 0.f, 0.f};
  v4f acc[4][2];
#pragma unroll
  for (int i = 0; i < 4; ++i) { acc[i][0] = vz; acc[i][1] = vz; }
#pragma unroll
  for (int nc = 0; nc < 4; ++nc) {
    __syncthreads();
    { // stage B rows nc*64..+64 of W2[b]
      const int row = tid >> 3, c0 = (tid & 7) * 32;
      const short* src = W2 + ((size_t)(b * 256 + nc * 64 + row)) * 256 + c0;
#pragma unroll
      for (int q = 0; q < 4; ++q) {
        const int col = c0 + q * 8;
        const int byo = (row * 512 + col * 2) ^ ((row & 7) << 4);
        *(v8s*)(sm + 32768 + byo) = *(const v8s*)(src + q * 8);
      }
    }
    __syncthreads();
#pragma unroll
    for (int ks = 0; ks < 8; ++ks) {
      const int kb2 = (ks * 32 + ((lane >> 4) * 8)) * 2;
      const int n = wn * 16 + (lane & 15);
      const int byoB = (n * 512 + kb2) ^ ((n & 7) << 4);
      const v8s bf = *(const v8s*)(sm + 32768 + byoB);
#pragma unroll
      for (int mi = 0; mi < 2; ++mi) {
        const int m = wm * 32 + mi * 16 + (lane & 15);
        const int byoA = (m * 512 + kb2) ^ ((m & 7) << 4);
        const v8s af = *(const v8s*)(sm + byoA);
        acc[nc][mi] = mfma16(af, bf, acc[nc][mi]);
      }
    }
  }
  // coalesced epilogue via LDS transpose (A region dead after last MFMA)
  float* st = (float*)sm;
#pragma unroll
  for (int ch = 0; ch < 2; ++ch) {
    __syncthreads();
#pragma unroll
    for (int nci = 0; nci < 2; ++nci)
#pragma unroll
      for (int mi = 0; mi < 2; ++mi)
#pragma unroll
        for (int r = 0; r < 4; ++r) {
          const int m = wm * 32 + mi * 16 + ((lane >> 4) * 4) + r;
          const int cw = nci * 64 + wn * 16 + (lane & 15);
          st[swzw(m, cw)] = acc[ch * 2 + nci][mi][r];
        }
    __syncthreads();
    const int base = tid * 4;
#pragma unroll
    for (int p = 0; p < 4; ++p) {
      const int flat = p * 2048 + base;
      const int row = flat >> 7, colw = flat & 127;
      const v4f t = *(const v4f*)(st + swzw(row, colw));
      *(v4f*)(out + (m0 + row) * 256 + ch * 128 + colw) = t;
    }
  }
}

extern "C" void kernel_launch(void* const* d_in, const int* in_sizes, int n_in,
                              void* d_out, int out_size, void* d_ws, size_t ws_size,
                              hipStream_t stream) {
  const float* x      = (const float*)d_in[0];
  const float* qkv_w  = (const float*)d_in[1];
  const float* dw_w   = (const float*)d_in[2];
  const float* proj_w = (const float*)d_in[3];
  const float* g1_w   = (const float*)d_in[4];
  const float* g1_b   = (const float*)d_in[5];
  const float* g2_w   = (const float*)d_in[6];
  const float* g2_b   = (const float*)d_in[7];
  const float* temp   = (const float*)d_in[8];
  const float* a1     = (const float*)d_in[9];
  const float* a2     = (const float*)d_in[10];
  const float* a3     = (const float*)d_in[11];
  const float* a4     = (const float*)d_in[12];
  float* out = (float*)d_out;
  char* ws = (char*)d_ws;

  double* gram  = (double*)(ws + OFF_GRAM);
  double* qn    = (double*)(ws + OFF_QN);
  double* kn    = (double*)(ws + OFF_KN);
  double* gsum  = (double*)(ws + OFF_GSUM);
  float*  attnw = (float*)(ws + OFF_ATTN);
  short*  wqh   = (short*)(ws + OFF_WQH);
  short*  wql   = (short*)(ws + OFF_WQL);
  short*  g1h   = (short*)(ws + OFF_G1H);
  short*  g1l   = (short*)(ws + OFF_G1L);
  short*  W2    = (short*)(ws + OFF_W2);
  float*  qkf   = (float*)(ws + OFF_QK);
  short*  vb    = (short*)(ws + OFF_V);
  short*  vbuf  = (short*)(ws + OFF_VOUT);

  hipMemsetAsync(ws, 0, 40960, stream);                       // gram/qn/kn/gsum accumulators
  k0_split<<<320, 256, 0, stream>>>(qkv_w, g1_w, wqh, wql, g1h, g1l);
  k1_qkv<<<2048, 512, 0, stream>>>(x, wqh, wql, qkf, vb);
  k1_g<<<2048, 512, 0, stream>>>(x, g1h, g1l, g1_b, g2_w, g2_b, gsum);
  k2_conv<<<dim3(256, 8, 2), 256, 0, stream>>>(qkf, vb, dw_w, gram, qn, kn, vbuf);
  k3a_attn<<<1, 256, 0, stream>>>(gram, qn, kn, gsum, temp, a1, a2, a3, a4, attnw);
  k3b_fold<<<dim3(256, 2), 256, 0, stream>>>(proj_w, attnw, W2);
  k4_out<<<2048, 512, 0, stream>>>(vbuf, x, W2, out);
  (void)in_sizes; (void)n_in; (void)out_size; (void)ws_size;
}

// Round 5
// 291.750 us; speedup vs baseline: 1.3252x; 1.3252x over previous
//
#include <hip/hip_runtime.h>
#include <cstdint>
#include <cstddef>

typedef __attribute__((ext_vector_type(4))) float v4f;
typedef __attribute__((ext_vector_type(8))) short v8s;
typedef __attribute__((ext_vector_type(4))) short v4s;

__device__ __forceinline__ short f2bf(float f) {
  unsigned u = __float_as_uint(f);
  u += 0x7FFFu + ((u >> 16) & 1u);   // round-to-nearest-even
  return (short)(u >> 16);
}
__device__ __forceinline__ float bf2f(short h) {
  return __uint_as_float(((unsigned)(unsigned short)h) << 16);
}
__device__ __forceinline__ v4f mfma16(v8s a, v8s b, v4f c) {
  return __builtin_amdgcn_mfma_f32_16x16x32_bf16(a, b, c, 0, 0, 0);
}

// ---------------- workspace layout (bytes) ----------------
#define OFF_GRAM   0u          // double[2*8*16*16] = 32768
#define OFF_QN     32768u      // double[256]
#define OFF_KN     34816u      // double[256]
#define OFF_GSUM   36864u      // double[1]
#define OFF_ATTN   40960u      // float[4096]
#define OFF_WQH    65536u      // short[6144*8] fragment-major qkv hi
#define OFF_WQL    163840u     // lo
#define OFF_G1H    262144u     // short[4096*8] fragment-major g1 hi
#define OFF_G1L    327680u
#define OFF_W2     393216u     // short[2*128*64*8] = 512KB fragment-major folded proj
#define OFF_QK     1048576u    // float[131072*256] pixel-major (q ch 0..127, k ch 128..255)
#define OFF_V      135266304u  // short[131072*128] pixel-major bf16 (raw v)
#define OFF_VOUT   168820736u  // short[131072*128] post-conv v

// K0: split fp32 weights into bf16 hi/lo planes, FRAGMENT-MAJOR:
// qkv: t=(g*4+ks)*64+l, g=n/16 (24), ks=k/32 (4); elem: n=g*16+(l&15), k=ks*32+(l>>4)*8, 8 elems
// g1:  t2=(g2*8+ks2)*64+l, g2=n/16 (8), ks2=k/32 (8)
__global__ void k0_split(const float* __restrict__ qkv_w, const float* __restrict__ g1_w,
                         short* __restrict__ wqh, short* __restrict__ wql,
                         short* __restrict__ g1h, short* __restrict__ g1l) {
  const int t = blockIdx.x * 256 + threadIdx.x;
  if (t < 6144) {
    const int l = t & 63, ks = (t >> 6) & 3, g = t >> 8;
    const int n = g * 16 + (l & 15), k = ks * 32 + (l >> 4) * 8;
    v8s hi, lo;
#pragma unroll
    for (int j = 0; j < 8; ++j) {
      const float f = qkv_w[n * 128 + k + j];
      const short h = f2bf(f);
      hi[j] = h; lo[j] = f2bf(f - bf2f(h));
    }
    *(v8s*)(wqh + (size_t)t * 8) = hi;
    *(v8s*)(wql + (size_t)t * 8) = lo;
  } else if (t < 10240) {
    const int t2 = t - 6144;
    const int l = t2 & 63, ks2 = (t2 >> 6) & 7, g2 = t2 >> 9;
    const int n = g2 * 16 + (l & 15), k = ks2 * 32 + (l >> 4) * 8;
    v8s hi, lo;
#pragma unroll
    for (int j = 0; j < 8; ++j) {
      const float f = g1_w[n * 256 + k + j];
      const short h = f2bf(f);
      hi[j] = h; lo[j] = f2bf(f - bf2f(h));
    }
    *(v8s*)(g1h + (size_t)t2 * 8) = hi;
    *(v8s*)(g1l + (size_t)t2 * 8) = lo;
  }
}

// K1: qkv = x1 @ Wqkv^T (M=131072, K=128, N=384). A staged to LDS hi/lo, A-hi in regs,
// A-lo read from LDS per step. B: fragment-major, 3-deep register pipeline, no B barriers.
// q,k: 3-term split-bf16 fp32 out (scattered stores, r3-proven). v: 1-term bf16 via vtr LDS.
__global__ __launch_bounds__(512, 4) void k1_qkv(const float* __restrict__ x,
                                                 const short* __restrict__ wqh,
                                                 const short* __restrict__ wql,
                                                 float* __restrict__ qkf,
                                                 short* __restrict__ vb) {
  __shared__ __align__(16) unsigned char sm[49152]; // Ah@0 Al@16384 vtr@32768
  const int tid = threadIdx.x;
  const size_t m0 = (size_t)blockIdx.x * 64;
  const int lane = tid & 63, wid = tid >> 6;
  const int wm = wid >> 2, wn = wid & 3;

  // B pipeline prologue: 3 fragment loads in flight before anything else
  v8s pbh[3], pbl[3];
#pragma unroll
  for (int s = 0; s < 3; ++s) {
    const size_t off = ((size_t)((0 * 4 + wn) * 4 + s) * 64 + lane) * 8; // nc=0, ks=s
    pbh[s] = *(const v8s*)(wqh + off);
    pbl[s] = *(const v8s*)(wql + off);
  }

  { // stage A = x rows, cols 0..127, hi/lo bf16, swizzled
    const int row = tid >> 3, c0 = (tid & 7) * 16;
    const float* src = x + (m0 + (size_t)row) * 256 + c0;
#pragma unroll
    for (int half = 0; half < 2; ++half) {
      v4f f0 = *(const v4f*)(src + half * 8);
      v4f f1 = *(const v4f*)(src + half * 8 + 4);
      v8s hi, lo;
#pragma unroll
      for (int j = 0; j < 4; ++j) {
        short h0 = f2bf(f0[j]); hi[j] = h0;   lo[j]   = f2bf(f0[j] - bf2f(h0));
        short h1 = f2bf(f1[j]); hi[4+j] = h1; lo[4+j] = f2bf(f1[j] - bf2f(h1));
      }
      const int col = c0 + half * 8;
      const int byo = (row * 256 + col * 2) ^ ((row & 7) << 4);
      *(v8s*)(sm + byo) = hi;
      *(v8s*)(sm + 16384 + byo) = lo;
    }
  }
  __syncthreads();
  // A-hi fragments -> registers (32 VGPR); A-lo stays in LDS
  v8s ah[4][2];
#pragma unroll
  for (int ks = 0; ks < 4; ++ks)
#pragma unroll
    for (int mi = 0; mi < 2; ++mi) {
      const int kb2 = (ks * 32 + ((lane >> 4) * 8)) * 2;
      const int m = wm * 32 + mi * 16 + (lane & 15);
      const int byoA = (m * 256 + kb2) ^ ((m & 7) << 4);
      ah[ks][mi] = *(const v8s*)(sm + byoA);
    }
  const v4f vz = {0.f, 0.f, 0.f, 0.f};
  v4f acc[6][2];
#pragma unroll
  for (int i = 0; i < 6; ++i) { acc[i][0] = vz; acc[i][1] = vz; }

#pragma unroll
  for (int s = 0; s < 24; ++s) {
    const int nc = s >> 2, ks = s & 3, slot = s % 3;
    const v8s bh = pbh[slot];
    const v8s bl = pbl[slot];
    if (s + 3 < 24) { // issue load for step s+3 into the just-consumed slot
      const int s3 = s + 3, nc3 = s3 >> 2, ks3 = s3 & 3;
      const size_t off = ((size_t)((nc3 * 4 + wn) * 4 + ks3) * 64 + lane) * 8;
      pbh[slot] = *(const v8s*)(wqh + off);
      if (nc3 < 4) pbl[slot] = *(const v8s*)(wql + off);
    }
#pragma unroll
    for (int mi = 0; mi < 2; ++mi) {
      const int kb2 = (ks * 32 + ((lane >> 4) * 8)) * 2;
      const int m = wm * 32 + mi * 16 + (lane & 15);
      const int byoA = (m * 256 + kb2) ^ ((m & 7) << 4);
      acc[nc][mi] = mfma16(ah[ks][mi], bh, acc[nc][mi]);
      if (nc < 4) {
        const v8s alv = *(const v8s*)(sm + 16384 + byoA);
        acc[nc][mi] = mfma16(alv, bh, acc[nc][mi]);
        acc[nc][mi] = mfma16(ah[ks][mi], bl, acc[nc][mi]);
      }
    }
  }
  // epilogue: q,k fp32 direct stores (r3-proven)
#pragma unroll
  for (int nc = 0; nc < 4; ++nc)
#pragma unroll
    for (int mi = 0; mi < 2; ++mi)
#pragma unroll
      for (int r = 0; r < 4; ++r) {
        const int m = wm * 32 + mi * 16 + ((lane >> 4) * 4) + r;
        const int n = nc * 64 + wn * 16 + (lane & 15);
        qkf[(m0 + m) * 256 + n] = acc[nc][mi][r];
      }
  // v -> bf16 via LDS transpose, coalesced 16B stores
  short* vtr = (short*)(sm + 32768);
#pragma unroll
  for (int nc = 4; nc < 6; ++nc)
#pragma unroll
    for (int mi = 0; mi < 2; ++mi)
#pragma unroll
      for (int r = 0; r < 4; ++r) {
        const int m = wm * 32 + mi * 16 + ((lane >> 4) * 4) + r;
        const int n = (nc - 4) * 64 + wn * 16 + (lane & 15);
        vtr[m * 128 + n] = f2bf(acc[nc][mi][r]);
      }
  __syncthreads();
  {
    const int base = tid * 8;   // shorts
#pragma unroll
    for (int p = 0; p < 2; ++p) {
      const int flat = p * 4096 + base;
      const int row = flat >> 7, col = flat & 127;
      const v8s t = *(const v8s*)(vtr + row * 128 + col);
      *(v8s*)(vb + (m0 + row) * 128 + col) = t;
    }
  }
}

// K1g: g1 = x @ W1^T (K=256,N=128) split-bf16 4-term (exact r1 accumulation order),
// fragment-major B with 3-deep pipeline; fused relu+g2 dot+sigmoid+mean (double atomic)
__global__ __launch_bounds__(512, 4) void k1_g(const float* __restrict__ x,
                                               const short* __restrict__ g1h,
                                               const short* __restrict__ g1l,
                                               const float* __restrict__ g1_b,
                                               const float* __restrict__ g2_w,
                                               const float* __restrict__ g2_b,
                                               double* __restrict__ gsum) {
  __shared__ __align__(16) unsigned char sm[32768]; // Ah@0 Al@16384
  const int tid = threadIdx.x;
  const size_t m0 = (size_t)blockIdx.x * 64;
  const int lane = tid & 63, wid = tid >> 6;
  const int wm = wid >> 2, wn = wid & 3;
  const v4f vz = {0.f, 0.f, 0.f, 0.f};
  v4f acc[2][2];
  acc[0][0] = vz; acc[0][1] = vz; acc[1][0] = vz; acc[1][1] = vz;
  v8s pbh[3], pbl[3];
#pragma unroll
  for (int kc = 0; kc < 2; ++kc) {
    // prologue loads for this kc (independent of LDS; issued before barrier)
#pragma unroll
    for (int s = 0; s < 3; ++s) {
      const int nc = s >> 2, ks = s & 3;   // s<3 -> nc=0
      const size_t off = ((size_t)((nc * 4 + wn) * 8 + kc * 4 + ks) * 64 + lane) * 8;
      pbh[s] = *(const v8s*)(g1h + off);
      pbl[s] = *(const v8s*)(g1l + off);
    }
    __syncthreads();
    { // stage A chunk (cols kc*128..+128) hi/lo
      const int row = tid >> 3, c0 = (tid & 7) * 16;
      const float* src = x + (m0 + (size_t)row) * 256 + kc * 128 + c0;
#pragma unroll
      for (int half = 0; half < 2; ++half) {
        v4f f0 = *(const v4f*)(src + half * 8);
        v4f f1 = *(const v4f*)(src + half * 8 + 4);
        v8s hi, lo;
#pragma unroll
        for (int j = 0; j < 4; ++j) {
          short h0 = f2bf(f0[j]); hi[j] = h0;   lo[j]   = f2bf(f0[j] - bf2f(h0));
          short h1 = f2bf(f1[j]); hi[4+j] = h1; lo[4+j] = f2bf(f1[j] - bf2f(h1));
        }
        const int col = c0 + half * 8;
        const int byo = (row * 256 + col * 2) ^ ((row & 7) << 4);
        *(v8s*)(sm + byo) = hi;
        *(v8s*)(sm + 16384 + byo) = lo;
      }
    }
    __syncthreads();
    v8s ah[4][2];
#pragma unroll
    for (int ks = 0; ks < 4; ++ks)
#pragma unroll
      for (int mi = 0; mi < 2; ++mi) {
        const int kb2 = (ks * 32 + ((lane >> 4) * 8)) * 2;
        const int m = wm * 32 + mi * 16 + (lane & 15);
        const int byoA = (m * 256 + kb2) ^ ((m & 7) << 4);
        ah[ks][mi] = *(const v8s*)(sm + byoA);
      }
#pragma unroll
    for (int s = 0; s < 8; ++s) {
      const int nc = s >> 2, ks = s & 3, slot = s % 3;
      const v8s bh = pbh[slot];
      const v8s bl = pbl[slot];
      if (s + 3 < 8) {
        const int s3 = s + 3, nc3 = s3 >> 2, ks3 = s3 & 3;
        const size_t off = ((size_t)((nc3 * 4 + wn) * 8 + kc * 4 + ks3) * 64 + lane) * 8;
        pbh[slot] = *(const v8s*)(g1h + off);
        pbl[slot] = *(const v8s*)(g1l + off);
      }
#pragma unroll
      for (int mi = 0; mi < 2; ++mi) {
        const int kb2 = (ks * 32 + ((lane >> 4) * 8)) * 2;
        const int m = wm * 32 + mi * 16 + (lane & 15);
        const int byoA = (m * 256 + kb2) ^ ((m & 7) << 4);
        const v8s alv = *(const v8s*)(sm + 16384 + byoA);
        acc[nc][mi] = mfma16(ah[ks][mi], bh, acc[nc][mi]);
        acc[nc][mi] = mfma16(alv, bh, acc[nc][mi]);
        acc[nc][mi] = mfma16(ah[ks][mi], bl, acc[nc][mi]);
        acc[nc][mi] = mfma16(alv, bl, acc[nc][mi]);
      }
    }
  }
  // epilogue: per-pixel g2 dot + sigmoid + block sum -> double atomic
  __syncthreads();
  float* g2ws = (float*)sm;           // aliases dead A region
  float* ldsg = (float*)(sm + 512);
  if (tid < 128) g2ws[tid] = g2_w[tid];
  if (tid < 64) ldsg[tid] = 0.f;
  __syncthreads();
  float bias[2], g2v[2];
#pragma unroll
  for (int nc = 0; nc < 2; ++nc) {
    const int n = nc * 64 + wn * 16 + (lane & 15);
    bias[nc] = g1_b[n];
    g2v[nc] = g2ws[n];
  }
#pragma unroll
  for (int mi = 0; mi < 2; ++mi)
#pragma unroll
    for (int r = 0; r < 4; ++r) {
      float part = 0.f;
#pragma unroll
      for (int nc = 0; nc < 2; ++nc) {
        float val = acc[nc][mi][r] + bias[nc];
        val = fmaxf(val, 0.f);
        part += val * g2v[nc];
      }
      part += __shfl_xor(part, 1, 16);
      part += __shfl_xor(part, 2, 16);
      part += __shfl_xor(part, 4, 16);
      part += __shfl_xor(part, 8, 16);
      if ((lane & 15) == 0)
        atomicAdd(&ldsg[wm * 32 + mi * 16 + ((lane >> 4) * 4) + r], part);
    }
  __syncthreads();
  if (tid < 64) {
    float pre = ldsg[tid] + g2_b[0];
    float g = 1.f / (1.f + expf(-pre));
#pragma unroll
    for (int mk = 1; mk < 64; mk <<= 1) g += __shfl_xor(g, mk, 64);
    if (tid == 0) atomicAdd(gsum, (double)g);
  }
}

// K2: thread = (channel, row). Fused dwconv + norms + gram + v write. (unchanged)
__global__ __launch_bounds__(256, 4) void k2_conv(const float* __restrict__ qkf,
                                                  const short* __restrict__ vb,
                                                  const float* __restrict__ dw_w,
                                                  double* __restrict__ gram,
                                                  double* __restrict__ qn,
                                                  double* __restrict__ kn,
                                                  short* __restrict__ vbuf) {
  __shared__ __align__(16) unsigned char SM[25984];
  float* haloT = (float*)SM;                 // [c][325]
  short* vtr   = (short*)SM;                 // alias, [px][24]
  float* wsm   = (float*)(SM + 20800);
  float* redQ  = (float*)(SM + 21376);
  float* redK  = (float*)(SM + 21632);
  float* gramW = (float*)(SM + 21888);

  const int tid = threadIdx.x;
  const int tile = blockIdx.x, h = blockIdx.y, b = blockIdx.z;
  const int px0 = (tile & 15) * 16, py0 = (tile >> 4) * 16;
  const int c = tid & 15, r = tid >> 4;
  const int lane = tid & 63, w4 = tid >> 6;

  auto stage = [&](int sec) {
    const int chbase = sec * 128 + h * 16;
#pragma unroll
    for (int i = 0; i < 6; ++i) {
      const int idx = tid + i * 256;
      if (idx < 1296) {
        const int p = idx >> 2, e4 = (idx & 3) * 4;
        const int row = p / 18, col = p - row * 18;
        const int gy = py0 - 1 + row, gx = px0 - 1 + col;
        v4f val = {0.f, 0.f, 0.f, 0.f};
        if (gy >= 0 && gy < 256 && gx >= 0 && gx < 256) {
          const size_t pix = (size_t)(b * 65536 + gy * 256 + gx);
          if (sec < 2) {
            val = *(const v4f*)(qkf + pix * 256 + sec * 128 + h * 16 + e4);
          } else {
            const v4s sv = *(const v4s*)(vb + pix * 128 + h * 16 + e4);
            val[0] = bf2f(sv[0]); val[1] = bf2f(sv[1]);
            val[2] = bf2f(sv[2]); val[3] = bf2f(sv[3]);
          }
        }
        haloT[(e4 + 0) * 325 + p] = val[0];
        haloT[(e4 + 1) * 325 + p] = val[1];
        haloT[(e4 + 2) * 325 + p] = val[2];
        haloT[(e4 + 3) * 325 + p] = val[3];
      }
    }
    if (tid < 144) wsm[tid] = dw_w[chbase * 9 + tid];
  };

  auto conv16 = [&](float* o) {
#pragma unroll
    for (int j = 0; j < 16; ++j) o[j] = 0.f;
#pragma unroll
    for (int dy = 0; dy < 3; ++dy) {
      const float* rp = haloT + c * 325 + (r + dy) * 18;
      float rowb[18];
#pragma unroll
      for (int xx = 0; xx < 18; ++xx) rowb[xx] = rp[xx];
      const float w0 = wsm[c * 9 + dy * 3 + 0];
      const float w1 = wsm[c * 9 + dy * 3 + 1];
      const float w2 = wsm[c * 9 + dy * 3 + 2];
#pragma unroll
      for (int j = 0; j < 16; ++j)
        o[j] += w0 * rowb[j] + w1 * rowb[j + 1] + w2 * rowb[j + 2];
    }
  };

  float qreg[16], kreg[16];

  stage(0);
  __syncthreads();
  conv16(qreg);
  {
    float s = 0.f;
#pragma unroll
    for (int j = 0; j < 16; ++j) s += qreg[j] * qreg[j];
    s += __shfl_xor(s, 16, 64);
    s += __shfl_xor(s, 32, 64);
    if (lane < 16) redQ[w4 * 16 + lane] = s;
  }
  __syncthreads();
  stage(1);
  __syncthreads();
  conv16(kreg);
  {
    float s = 0.f;
#pragma unroll
    for (int j = 0; j < 16; ++j) s += kreg[j] * kreg[j];
    s += __shfl_xor(s, 16, 64);
    s += __shfl_xor(s, 32, 64);
    if (lane < 16) redK[w4 * 16 + lane] = s;
  }
  {
    v4f acc = {0.f, 0.f, 0.f, 0.f};
    const int qt = lane >> 4;
    const bool hiHalf = (qt & 1);
#pragma unroll
    for (int f = 0; f < 2; ++f) {
      const int src = ((f * 2 + (qt >> 1)) << 4) | (lane & 15);
      v8s qh, ql, kh, kl;
#pragma unroll
      for (int j = 0; j < 8; ++j) {
        const float qa = __shfl(qreg[j], src, 64);
        const float qb = __shfl(qreg[j + 8], src, 64);
        const float ka = __shfl(kreg[j], src, 64);
        const float kb = __shfl(kreg[j + 8], src, 64);
        const float qv = hiHalf ? qb : qa;
        const float kv = hiHalf ? kb : ka;
        const short h1 = f2bf(qv); qh[j] = h1; ql[j] = f2bf(qv - bf2f(h1));
        const short h2 = f2bf(kv); kh[j] = h2; kl[j] = f2bf(kv - bf2f(h2));
      }
      acc = mfma16(qh, kh, acc);
      acc = mfma16(ql, kh, acc);
      acc = mfma16(qh, kl, acc);
      acc = mfma16(ql, kl, acc);
    }
#pragma unroll
    for (int rr = 0; rr < 4; ++rr)
      gramW[w4 * 256 + (qt * 4 + rr) * 16 + (lane & 15)] = acc[rr];
  }
  __syncthreads();
  stage(2);
  __syncthreads();
  float vv[16];
  conv16(vv);
  if (tid < 16) {
    const float t = redQ[tid] + redQ[16 + tid] + redQ[32 + tid] + redQ[48 + tid];
    atomicAdd(&qn[b * 128 + h * 16 + tid], (double)t);
  } else if (tid < 32) {
    const int cc = tid - 16;
    const float t = redK[cc] + redK[16 + cc] + redK[32 + cc] + redK[48 + cc];
    atomicAdd(&kn[b * 128 + h * 16 + cc], (double)t);
  }
  {
    const float g = gramW[tid] + gramW[256 + tid] + gramW[512 + tid] + gramW[768 + tid];
    atomicAdd(&gram[(size_t)(b * 8 + h) * 256 + tid], (double)g);
  }
  __syncthreads();
  {
#pragma unroll
    for (int j = 0; j < 16; ++j) vtr[(r * 16 + j) * 24 + c] = f2bf(vv[j]);
  }
  __syncthreads();
  {
    const v8s o0 = *(const v8s*)(vtr + tid * 24);
    const v8s o1 = *(const v8s*)(vtr + tid * 24 + 8);
    short* dst = vbuf + ((size_t)b * 65536 + (size_t)(py0 + (tid >> 4)) * 256 + (px0 + (tid & 15))) * 128 + h * 16;
    *(v8s*)dst = o0;
    *(v8s*)(dst + 8) = o1;
  }
}

// K3a: normalize gram -> cosine attn, temperature, dyn_k top-k mask, softmax, *sum(attn1..4)
__global__ void k3a_attn(const double* __restrict__ gram, const double* __restrict__ qn,
                         const double* __restrict__ kn, const double* __restrict__ gsum,
                         const float* __restrict__ temp,
                         const float* __restrict__ a1p, const float* __restrict__ a2p,
                         const float* __restrict__ a3p, const float* __restrict__ a4p,
                         float* __restrict__ attnw) {
  const int t = threadIdx.x;  // 256 rows: (b,h,c)
  const int b = t >> 7, rem = t & 127, h = rem >> 4, c = rem & 15;
  const float qnv = fmaxf(sqrtf((float)qn[b * 128 + h * 16 + c]), 1e-12f);
  const float tv = temp[h];
  float a[16];
#pragma unroll
  for (int d = 0; d < 16; ++d) {
    const float knv = fmaxf(sqrtf((float)kn[b * 128 + h * 16 + d]), 1e-12f);
    a[d] = (float)gram[(size_t)(b * 8 + h) * 256 + c * 16 + d] / (qnv * knv) * tv;
  }
  const float dynk = floorf(16.f * (float)(gsum[0] / 131072.0));
  float mx = -INFINITY;
  bool keep[16];
#pragma unroll
  for (int d = 0; d < 16; ++d) {
    int rank = 0;
#pragma unroll
    for (int e = 0; e < 16; ++e)
      rank += ((a[e] > a[d]) || ((a[e] == a[d]) && (e < d))) ? 1 : 0;
    keep[d] = ((float)rank < dynk);
    if (keep[d]) mx = fmaxf(mx, a[d]);
  }
  float ssum = 0.f, wvv[16];
#pragma unroll
  for (int d = 0; d < 16; ++d) {
    wvv[d] = keep[d] ? expf(a[d] - mx) : 0.f;
    ssum += wvv[d];
  }
  const float satt = a1p[0] + a2p[0] + a3p[0] + a4p[0];
  const float sc = satt / ssum;
#pragma unroll
  for (int d = 0; d < 16; ++d) attnw[t * 16 + d] = wvv[d] * sc;
}

// K3b: fold attention into projection, FRAGMENT-MAJOR bf16 out:
// W2f[((b*128 + g*8 + ks)*64 + lane)*8 + j], n=g*16+(lane&15), k=ks*32+(lane>>4)*8+j
__global__ void k3b_fold(const float* __restrict__ proj_w, const float* __restrict__ attnw,
                         short* __restrict__ W2f) {
  const int g = blockIdx.x, b = blockIdx.y;
  const int ks = threadIdx.x >> 6, lane = threadIdx.x & 63;
  const int o = g * 16 + (lane & 15);
  const int k0 = ks * 32 + (lane >> 4) * 8;
  v8s outv;
  if (k0 < 128) {
    const int h = k0 >> 4, d0 = k0 & 15;
    float s[8];
#pragma unroll
    for (int j = 0; j < 8; ++j) s[j] = 0.f;
#pragma unroll
    for (int i = 0; i < 16; ++i) {
      const float pw = proj_w[o * 256 + h * 16 + i];
#pragma unroll
      for (int j = 0; j < 8; ++j)
        s[j] += pw * attnw[((b * 8 + h) * 16 + i) * 16 + d0 + j];
    }
#pragma unroll
    for (int j = 0; j < 8; ++j) outv[j] = f2bf(s[j]);
  } else {
#pragma unroll
    for (int j = 0; j < 8; ++j) outv[j] = f2bf(proj_w[o * 256 + k0 + j]);
  }
  *(v8s*)(W2f + ((size_t)(b * 128 + g * 8 + ks) * 64 + lane) * 8) = outv;
}

// K4: out[m][o] = [v(m);x2(m)] @ W2[b]^T (M=131072,K=256,N=256). A staged once (LDS),
// A-frags in regs; B fragment-major 3-deep pipeline, no mid-loop barriers; direct stores.
__global__ __launch_bounds__(512, 4) void k4_out(const short* __restrict__ vbuf,
                                                 const float* __restrict__ x,
                                                 const short* __restrict__ W2f,
                                                 float* __restrict__ out) {
  __shared__ __align__(16) unsigned char sm[32768]; // A [64][256] bf16 swizzled
  const int tid = threadIdx.x;
  const size_t m0 = (size_t)blockIdx.x * 64;
  const int b = (int)(m0 >> 16);
  const int lane = tid & 63, wid = tid >> 6;
  const int wm = wid >> 2, wn = wid & 3;

  v8s pbB[3];
#pragma unroll
  for (int s = 0; s < 3; ++s) { // nc=0, ks=s
    const size_t off = ((size_t)(b * 128 + (0 * 4 + wn) * 8 + s) * 64 + lane) * 8;
    pbB[s] = *(const v8s*)(W2f + off);
  }
  {
    const int row = tid >> 3, c0 = (tid & 7) * 16;
    { // cols 0..127 from v (already bf16)
      const short* src = vbuf + (m0 + (size_t)row) * 128 + c0;
#pragma unroll
      for (int half = 0; half < 2; ++half) {
        const int col = c0 + half * 8;
        const int byo = (row * 512 + col * 2) ^ ((row & 7) << 4);
        *(v8s*)(sm + byo) = *(const v8s*)(src + half * 8);
      }
    }
    { // cols 128..255 from x2 (fp32 -> bf16)
      const float* src = x + (m0 + (size_t)row) * 256 + 128 + c0;
#pragma unroll
      for (int half = 0; half < 2; ++half) {
        v4f f0 = *(const v4f*)(src + half * 8);
        v4f f1 = *(const v4f*)(src + half * 8 + 4);
        v8s hv;
#pragma unroll
        for (int j = 0; j < 4; ++j) { hv[j] = f2bf(f0[j]); hv[4+j] = f2bf(f1[j]); }
        const int col = 128 + c0 + half * 8;
        const int byo = (row * 512 + col * 2) ^ ((row & 7) << 4);
        *(v8s*)(sm + byo) = hv;
      }
    }
  }
  __syncthreads();
  v8s af[8][2];
#pragma unroll
  for (int ks = 0; ks < 8; ++ks)
#pragma unroll
    for (int mi = 0; mi < 2; ++mi) {
      const int kb2 = (ks * 32 + ((lane >> 4) * 8)) * 2;
      const int m = wm * 32 + mi * 16 + (lane & 15);
      const int byoA = (m * 512 + kb2) ^ ((m & 7) << 4);
      af[ks][mi] = *(const v8s*)(sm + byoA);
    }
  const v4f vz = {0.f, 0.f, 0.f, 0.f};
  v4f acc[4][2];
#pragma unroll
  for (int i = 0; i < 4; ++i) { acc[i][0] = vz; acc[i][1] = vz; }
#pragma unroll
  for (int s = 0; s < 32; ++s) {
    const int nc = s >> 3, ks = s & 7, slot = s % 3;
    const v8s bf = pbB[slot];
    if (s + 3 < 32) {
      const int s3 = s + 3, nc3 = s3 >> 3, ks3 = s3 & 7;
      const size_t off = ((size_t)(b * 128 + (nc3 * 4 + wn) * 8 + ks3) * 64 + lane) * 8;
      pbB[slot] = *(const v8s*)(W2f + off);
    }
#pragma unroll
    for (int mi = 0; mi < 2; ++mi)
      acc[nc][mi] = mfma16(af[ks][mi], bf, acc[nc][mi]);
  }
#pragma unroll
  for (int nc = 0; nc < 4; ++nc)
#pragma unroll
    for (int mi = 0; mi < 2; ++mi)
#pragma unroll
      for (int r = 0; r < 4; ++r) {
        const int m = wm * 32 + mi * 16 + ((lane >> 4) * 4) + r;
        const int o = nc * 64 + wn * 16 + (lane & 15);
        out[(m0 + m) * 256 + o] = acc[nc][mi][r];
      }
}

extern "C" void kernel_launch(void* const* d_in, const int* in_sizes, int n_in,
                              void* d_out, int out_size, void* d_ws, size_t ws_size,
                              hipStream_t stream) {
  const float* x      = (const float*)d_in[0];
  const float* qkv_w  = (const float*)d_in[1];
  const float* dw_w   = (const float*)d_in[2];
  const float* proj_w = (const float*)d_in[3];
  const float* g1_w   = (const float*)d_in[4];
  const float* g1_b   = (const float*)d_in[5];
  const float* g2_w   = (const float*)d_in[6];
  const float* g2_b   = (const float*)d_in[7];
  const float* temp   = (const float*)d_in[8];
  const float* a1     = (const float*)d_in[9];
  const float* a2     = (const float*)d_in[10];
  const float* a3     = (const float*)d_in[11];
  const float* a4     = (const float*)d_in[12];
  float* out = (float*)d_out;
  char* ws = (char*)d_ws;

  double* gram  = (double*)(ws + OFF_GRAM);
  double* qn    = (double*)(ws + OFF_QN);
  double* kn    = (double*)(ws + OFF_KN);
  double* gsum  = (double*)(ws + OFF_GSUM);
  float*  attnw = (float*)(ws + OFF_ATTN);
  short*  wqh   = (short*)(ws + OFF_WQH);
  short*  wql   = (short*)(ws + OFF_WQL);
  short*  g1h   = (short*)(ws + OFF_G1H);
  short*  g1l   = (short*)(ws + OFF_G1L);
  short*  W2f   = (short*)(ws + OFF_W2);
  float*  qkf   = (float*)(ws + OFF_QK);
  short*  vb    = (short*)(ws + OFF_V);
  short*  vbuf  = (short*)(ws + OFF_VOUT);

  hipMemsetAsync(ws, 0, 40960, stream);                       // gram/qn/kn/gsum accumulators
  k0_split<<<40, 256, 0, stream>>>(qkv_w, g1_w, wqh, wql, g1h, g1l);
  k1_qkv<<<2048, 512, 0, stream>>>(x, wqh, wql, qkf, vb);
  k1_g<<<2048, 512, 0, stream>>>(x, g1h, g1l, g1_b, g2_w, g2_b, gsum);
  k2_conv<<<dim3(256, 8, 2), 256, 0, stream>>>(qkf, vb, dw_w, gram, qn, kn, vbuf);
  k3a_attn<<<1, 256, 0, stream>>>(gram, qn, kn, gsum, temp, a1, a2, a3, a4, attnw);
  k3b_fold<<<dim3(16, 2), 512, 0, stream>>>(proj_w, attnw, W2f);
  k4_out<<<2048, 512, 0, stream>>>(vbuf, x, W2f, out);
  (void)in_sizes; (void)n_in; (void)out_size; (void)ws_size;
}

// Round 6
// 280.128 us; speedup vs baseline: 1.3802x; 1.0415x over previous
//
#include <hip/hip_runtime.h>
#include <hip/hip_bf16.h>
#include <cstdint>
#include <cstddef>

typedef __attribute__((ext_vector_type(4))) float v4f;
typedef __attribute__((ext_vector_type(8))) short v8s;
typedef __attribute__((ext_vector_type(4))) short v4s;
typedef __attribute__((ext_vector_type(4))) unsigned v4u;

__device__ __forceinline__ short f2bf(float f) {
  unsigned u = __float_as_uint(f);
  u += 0x7FFFu + ((u >> 16) & 1u);   // round-to-nearest-even
  return (short)(u >> 16);
}
__device__ __forceinline__ float bf2f(short h) {
  return __uint_as_float(((unsigned)(unsigned short)h) << 16);
}
__device__ __forceinline__ v4f mfma16(v8s a, v8s b, v4f c) {
  return __builtin_amdgcn_mfma_f32_16x16x32_bf16(a, b, c, 0, 0, 0);
}
// packed RNE f32x2 -> bf16x2 (low word = a)
__device__ __forceinline__ unsigned pack_rn(float a, float b) {
  __hip_bfloat162 p = __float22bfloat162_rn(make_float2(a, b));
  union { __hip_bfloat162 v; unsigned u; } c; c.v = p; return c.u;
}
// trunc-hi split of a pair: a=hi+lo (hi exact bf16 via truncation, lo RNE bf16)
struct u2 { unsigned h, l; };
__device__ __forceinline__ u2 split2pk(float a, float b) {
  const unsigned ua = __float_as_uint(a) & 0xffff0000u;
  const unsigned ub = __float_as_uint(b) & 0xffff0000u;
  const float la = a - __uint_as_float(ua);
  const float lb = b - __uint_as_float(ub);
  u2 r;
  r.h = (ua >> 16) | ub;
  r.l = pack_rn(la, lb);
  return r;
}

// ---------------- workspace layout (bytes) ----------------
#define OFF_GRAM   0u          // double[2*8*16*16] = 32768
#define OFF_QN     32768u      // double[256]
#define OFF_KN     34816u      // double[256]
#define OFF_GSUM   36864u      // double[1]
#define OFF_ATTN   40960u      // float[4096]
#define OFF_WQH    65536u      // short[6144*8] fragment-major qkv hi
#define OFF_WQL    163840u     // lo
#define OFF_G1H    262144u     // short[4096*8] fragment-major g1 hi
#define OFF_G1L    327680u
#define OFF_W2     393216u     // short[2*128*64*8] = 512KB fragment-major folded proj
#define OFF_QK     1048576u    // float[131072*256] pixel-major (q ch 0..127, k ch 128..255)
#define OFF_V      135266304u  // short[131072*128] pixel-major bf16 (raw v)
#define OFF_VOUT   168820736u  // short[131072*128] post-conv v

// K0: split fp32 weights into bf16 hi/lo planes (RNE), FRAGMENT-MAJOR
__global__ void k0_split(const float* __restrict__ qkv_w, const float* __restrict__ g1_w,
                         short* __restrict__ wqh, short* __restrict__ wql,
                         short* __restrict__ g1h, short* __restrict__ g1l) {
  const int t = blockIdx.x * 256 + threadIdx.x;
  if (t < 6144) {
    const int l = t & 63, ks = (t >> 6) & 3, g = t >> 8;
    const int n = g * 16 + (l & 15), k = ks * 32 + (l >> 4) * 8;
    v8s hi, lo;
#pragma unroll
    for (int j = 0; j < 8; ++j) {
      const float f = qkv_w[n * 128 + k + j];
      const short h = f2bf(f);
      hi[j] = h; lo[j] = f2bf(f - bf2f(h));
    }
    *(v8s*)(wqh + (size_t)t * 8) = hi;
    *(v8s*)(wql + (size_t)t * 8) = lo;
  } else if (t < 10240) {
    const int t2 = t - 6144;
    const int l = t2 & 63, ks2 = (t2 >> 6) & 7, g2 = t2 >> 9;
    const int n = g2 * 16 + (l & 15), k = ks2 * 32 + (l >> 4) * 8;
    v8s hi, lo;
#pragma unroll
    for (int j = 0; j < 8; ++j) {
      const float f = g1_w[n * 256 + k + j];
      const short h = f2bf(f);
      hi[j] = h; lo[j] = f2bf(f - bf2f(h));
    }
    *(v8s*)(g1h + (size_t)t2 * 8) = hi;
    *(v8s*)(g1l + (size_t)t2 * 8) = lo;
  }
}

// K1: qkv = x1 @ Wqkv^T (M=131072, K=128, N=384). A staged to LDS hi/lo (cheap trunc split),
// A-hi in regs, A-lo from LDS; B fragment-major 3-deep register pipeline.
__global__ __launch_bounds__(512, 4) void k1_qkv(const float* __restrict__ x,
                                                 const short* __restrict__ wqh,
                                                 const short* __restrict__ wql,
                                                 float* __restrict__ qkf,
                                                 short* __restrict__ vb) {
  __shared__ __align__(16) unsigned char sm[49152]; // Ah@0 Al@16384 vtr@32768
  const int tid = threadIdx.x;
  const size_t m0 = (size_t)blockIdx.x * 64;
  const int lane = tid & 63, wid = tid >> 6;
  const int wm = wid >> 2, wn = wid & 3;

  v8s pbh[3], pbl[3];
#pragma unroll
  for (int s = 0; s < 3; ++s) {
    const size_t off = ((size_t)((0 * 4 + wn) * 4 + s) * 64 + lane) * 8;
    pbh[s] = *(const v8s*)(wqh + off);
    pbl[s] = *(const v8s*)(wql + off);
  }

  { // stage A (trunc-hi split, packed)
    const int row = tid >> 3, c0 = (tid & 7) * 16;
    const float* src = x + (m0 + (size_t)row) * 256 + c0;
#pragma unroll
    for (int half = 0; half < 2; ++half) {
      v4f f0 = *(const v4f*)(src + half * 8);
      v4f f1 = *(const v4f*)(src + half * 8 + 4);
      v4u hi, lo;
      u2 t0 = split2pk(f0[0], f0[1]); hi[0] = t0.h; lo[0] = t0.l;
      u2 t1 = split2pk(f0[2], f0[3]); hi[1] = t1.h; lo[1] = t1.l;
      u2 t2 = split2pk(f1[0], f1[1]); hi[2] = t2.h; lo[2] = t2.l;
      u2 t3 = split2pk(f1[2], f1[3]); hi[3] = t3.h; lo[3] = t3.l;
      const int col = c0 + half * 8;
      const int byo = (row * 256 + col * 2) ^ ((row & 7) << 4);
      *(v4u*)(sm + byo) = hi;
      *(v4u*)(sm + 16384 + byo) = lo;
    }
  }
  __syncthreads();
  v8s ah[4][2];
#pragma unroll
  for (int ks = 0; ks < 4; ++ks)
#pragma unroll
    for (int mi = 0; mi < 2; ++mi) {
      const int kb2 = (ks * 32 + ((lane >> 4) * 8)) * 2;
      const int m = wm * 32 + mi * 16 + (lane & 15);
      const int byoA = (m * 256 + kb2) ^ ((m & 7) << 4);
      ah[ks][mi] = *(const v8s*)(sm + byoA);
    }
  const v4f vz = {0.f, 0.f, 0.f, 0.f};
  v4f acc[6][2];
#pragma unroll
  for (int i = 0; i < 6; ++i) { acc[i][0] = vz; acc[i][1] = vz; }

#pragma unroll
  for (int s = 0; s < 24; ++s) {
    const int nc = s >> 2, ks = s & 3, slot = s % 3;
    const v8s bh = pbh[slot];
    const v8s bl = pbl[slot];
    if (s + 3 < 24) {
      const int s3 = s + 3, nc3 = s3 >> 2, ks3 = s3 & 3;
      const size_t off = ((size_t)((nc3 * 4 + wn) * 4 + ks3) * 64 + lane) * 8;
      pbh[slot] = *(const v8s*)(wqh + off);
      if (nc3 < 4) pbl[slot] = *(const v8s*)(wql + off);
    }
#pragma unroll
    for (int mi = 0; mi < 2; ++mi) {
      const int kb2 = (ks * 32 + ((lane >> 4) * 8)) * 2;
      const int m = wm * 32 + mi * 16 + (lane & 15);
      const int byoA = (m * 256 + kb2) ^ ((m & 7) << 4);
      acc[nc][mi] = mfma16(ah[ks][mi], bh, acc[nc][mi]);
      if (nc < 4) {
        const v8s alv = *(const v8s*)(sm + 16384 + byoA);
        acc[nc][mi] = mfma16(alv, bh, acc[nc][mi]);
        acc[nc][mi] = mfma16(ah[ks][mi], bl, acc[nc][mi]);
      }
    }
  }
#pragma unroll
  for (int nc = 0; nc < 4; ++nc)
#pragma unroll
    for (int mi = 0; mi < 2; ++mi)
#pragma unroll
      for (int r = 0; r < 4; ++r) {
        const int m = wm * 32 + mi * 16 + ((lane >> 4) * 4) + r;
        const int n = nc * 64 + wn * 16 + (lane & 15);
        qkf[(m0 + m) * 256 + n] = acc[nc][mi][r];
      }
  short* vtr = (short*)(sm + 32768);
#pragma unroll
  for (int nc = 4; nc < 6; ++nc)
#pragma unroll
    for (int mi = 0; mi < 2; ++mi)
#pragma unroll
      for (int r = 0; r < 4; ++r) {
        const int m = wm * 32 + mi * 16 + ((lane >> 4) * 4) + r;
        const int n = (nc - 4) * 64 + wn * 16 + (lane & 15);
        vtr[m * 128 + n] = f2bf(acc[nc][mi][r]);
      }
  __syncthreads();
  {
    const int base = tid * 8;
#pragma unroll
    for (int p = 0; p < 2; ++p) {
      const int flat = p * 4096 + base;
      const int row = flat >> 7, col = flat & 127;
      const v8s t = *(const v8s*)(vtr + row * 128 + col);
      *(v8s*)(vb + (m0 + row) * 128 + col) = t;
    }
  }
}

// K1g: g1 = x @ W1^T (K=256,N=128) split-bf16 4-term; fragment-major B pipeline;
// fused relu+g2 dot+sigmoid+mean (double atomic)
__global__ __launch_bounds__(512, 4) void k1_g(const float* __restrict__ x,
                                               const short* __restrict__ g1h,
                                               const short* __restrict__ g1l,
                                               const float* __restrict__ g1_b,
                                               const float* __restrict__ g2_w,
                                               const float* __restrict__ g2_b,
                                               double* __restrict__ gsum) {
  __shared__ __align__(16) unsigned char sm[32768];
  const int tid = threadIdx.x;
  const size_t m0 = (size_t)blockIdx.x * 64;
  const int lane = tid & 63, wid = tid >> 6;
  const int wm = wid >> 2, wn = wid & 3;
  const v4f vz = {0.f, 0.f, 0.f, 0.f};
  v4f acc[2][2];
  acc[0][0] = vz; acc[0][1] = vz; acc[1][0] = vz; acc[1][1] = vz;
  v8s pbh[3], pbl[3];
#pragma unroll
  for (int kc = 0; kc < 2; ++kc) {
#pragma unroll
    for (int s = 0; s < 3; ++s) {
      const int nc = s >> 2, ks = s & 3;
      const size_t off = ((size_t)((nc * 4 + wn) * 8 + kc * 4 + ks) * 64 + lane) * 8;
      pbh[s] = *(const v8s*)(g1h + off);
      pbl[s] = *(const v8s*)(g1l + off);
    }
    __syncthreads();
    {
      const int row = tid >> 3, c0 = (tid & 7) * 16;
      const float* src = x + (m0 + (size_t)row) * 256 + kc * 128 + c0;
#pragma unroll
      for (int half = 0; half < 2; ++half) {
        v4f f0 = *(const v4f*)(src + half * 8);
        v4f f1 = *(const v4f*)(src + half * 8 + 4);
        v4u hi, lo;
        u2 t0 = split2pk(f0[0], f0[1]); hi[0] = t0.h; lo[0] = t0.l;
        u2 t1 = split2pk(f0[2], f0[3]); hi[1] = t1.h; lo[1] = t1.l;
        u2 t2 = split2pk(f1[0], f1[1]); hi[2] = t2.h; lo[2] = t2.l;
        u2 t3 = split2pk(f1[2], f1[3]); hi[3] = t3.h; lo[3] = t3.l;
        const int col = c0 + half * 8;
        const int byo = (row * 256 + col * 2) ^ ((row & 7) << 4);
        *(v4u*)(sm + byo) = hi;
        *(v4u*)(sm + 16384 + byo) = lo;
      }
    }
    __syncthreads();
    v8s ah[4][2];
#pragma unroll
    for (int ks = 0; ks < 4; ++ks)
#pragma unroll
      for (int mi = 0; mi < 2; ++mi) {
        const int kb2 = (ks * 32 + ((lane >> 4) * 8)) * 2;
        const int m = wm * 32 + mi * 16 + (lane & 15);
        const int byoA = (m * 256 + kb2) ^ ((m & 7) << 4);
        ah[ks][mi] = *(const v8s*)(sm + byoA);
      }
#pragma unroll
    for (int s = 0; s < 8; ++s) {
      const int nc = s >> 2, ks = s & 3, slot = s % 3;
      const v8s bh = pbh[slot];
      const v8s bl = pbl[slot];
      if (s + 3 < 8) {
        const int s3 = s + 3, nc3 = s3 >> 2, ks3 = s3 & 3;
        const size_t off = ((size_t)((nc3 * 4 + wn) * 8 + kc * 4 + ks3) * 64 + lane) * 8;
        pbh[slot] = *(const v8s*)(g1h + off);
        pbl[slot] = *(const v8s*)(g1l + off);
      }
#pragma unroll
      for (int mi = 0; mi < 2; ++mi) {
        const int kb2 = (ks * 32 + ((lane >> 4) * 8)) * 2;
        const int m = wm * 32 + mi * 16 + (lane & 15);
        const int byoA = (m * 256 + kb2) ^ ((m & 7) << 4);
        const v8s alv = *(const v8s*)(sm + 16384 + byoA);
        acc[nc][mi] = mfma16(ah[ks][mi], bh, acc[nc][mi]);
        acc[nc][mi] = mfma16(alv, bh, acc[nc][mi]);
        acc[nc][mi] = mfma16(ah[ks][mi], bl, acc[nc][mi]);
        acc[nc][mi] = mfma16(alv, bl, acc[nc][mi]);
      }
    }
  }
  __syncthreads();
  float* g2ws = (float*)sm;
  float* ldsg = (float*)(sm + 512);
  if (tid < 128) g2ws[tid] = g2_w[tid];
  if (tid < 64) ldsg[tid] = 0.f;
  __syncthreads();
  float bias[2], g2v[2];
#pragma unroll
  for (int nc = 0; nc < 2; ++nc) {
    const int n = nc * 64 + wn * 16 + (lane & 15);
    bias[nc] = g1_b[n];
    g2v[nc] = g2ws[n];
  }
#pragma unroll
  for (int mi = 0; mi < 2; ++mi)
#pragma unroll
    for (int r = 0; r < 4; ++r) {
      float part = 0.f;
#pragma unroll
      for (int nc = 0; nc < 2; ++nc) {
        float val = acc[nc][mi][r] + bias[nc];
        val = fmaxf(val, 0.f);
        part += val * g2v[nc];
      }
      part += __shfl_xor(part, 1, 16);
      part += __shfl_xor(part, 2, 16);
      part += __shfl_xor(part, 4, 16);
      part += __shfl_xor(part, 8, 16);
      if ((lane & 15) == 0)
        atomicAdd(&ldsg[wm * 32 + mi * 16 + ((lane >> 4) * 4) + r], part);
    }
  __syncthreads();
  if (tid < 64) {
    float pre = ldsg[tid] + g2_b[0];
    float g = 1.f / (1.f + expf(-pre));
#pragma unroll
    for (int mk = 1; mk < 64; mk <<= 1) g += __shfl_xor(g, mk, 64);
    if (tid == 0) atomicAdd(gsum, (double)g);
  }
}

// K2: thread = (channel, row). Fused dwconv + norms + gram + v write.
// Halo layout [c][row][20] (plane stride 364) -> b128 conv reads; async-stage split;
// trunc-split + cvt_pk in gram.
__global__ __launch_bounds__(256, 4) void k2_conv(const float* __restrict__ qkf,
                                                  const short* __restrict__ vb,
                                                  const float* __restrict__ dw_w,
                                                  double* __restrict__ gram,
                                                  double* __restrict__ qn,
                                                  double* __restrict__ kn,
                                                  short* __restrict__ vbuf) {
  __shared__ __align__(16) unsigned char SM[28480];
  float* haloT = (float*)SM;                 // [16 c][18 row][20 col] stride 364
  short* vtr   = (short*)SM;                 // alias, [px][24]
  float* wsm   = (float*)(SM + 23296);       // [16][9]
  float* redQ  = (float*)(SM + 23872);       // [wave][16]
  float* redK  = (float*)(SM + 24128);
  float* gramW = (float*)(SM + 24384);       // [wave][256]

  const int tid = threadIdx.x;
  const int tile = blockIdx.x, h = blockIdx.y, b = blockIdx.z;
  const int px0 = (tile & 15) * 16, py0 = (tile >> 4) * 16;
  const int c = tid & 15, r = tid >> 4;
  const int lane = tid & 63, w4 = tid >> 6;

  // load phase: global -> regs (issued early, latency hides under compute)
  auto stage_load = [&](int sec, v4f* vals) {
    const int chbase = sec * 128 + h * 16;
#pragma unroll
    for (int i = 0; i < 6; ++i) {
      const int idx = tid + i * 256;
      v4f val = {0.f, 0.f, 0.f, 0.f};
      if (idx < 1296) {
        const int p = idx >> 2, e4 = (idx & 3) * 4;
        const int row = p / 18, col = p - row * 18;
        const int gy = py0 - 1 + row, gx = px0 - 1 + col;
        if (gy >= 0 && gy < 256 && gx >= 0 && gx < 256) {
          const size_t pix = (size_t)(b * 65536 + gy * 256 + gx);
          if (sec < 2) {
            val = *(const v4f*)(qkf + pix * 256 + sec * 128 + h * 16 + e4);
          } else {
            const v4s sv = *(const v4s*)(vb + pix * 128 + h * 16 + e4);
            val[0] = bf2f(sv[0]); val[1] = bf2f(sv[1]);
            val[2] = bf2f(sv[2]); val[3] = bf2f(sv[3]);
          }
        }
      }
      vals[i] = val;
    }
  };
  // write phase: regs -> LDS (after barrier)
  auto stage_write = [&](int sec, const v4f* vals) {
#pragma unroll
    for (int i = 0; i < 6; ++i) {
      const int idx = tid + i * 256;
      if (idx < 1296) {
        const int p = idx >> 2, e4 = (idx & 3) * 4;
        const int row = p / 18, col = p - row * 18;
        haloT[(e4 + 0) * 364 + row * 20 + col] = vals[i][0];
        haloT[(e4 + 1) * 364 + row * 20 + col] = vals[i][1];
        haloT[(e4 + 2) * 364 + row * 20 + col] = vals[i][2];
        haloT[(e4 + 3) * 364 + row * 20 + col] = vals[i][3];
      }
    }
    if (tid < 144) wsm[tid] = dw_w[(sec * 128 + h * 16) * 9 + tid];
  };

  auto conv16 = [&](float* o) {
#pragma unroll
    for (int j = 0; j < 16; ++j) o[j] = 0.f;
#pragma unroll
    for (int dy = 0; dy < 3; ++dy) {
      const float* rp = haloT + c * 364 + (r + dy) * 20;
      const v4f t0 = *(const v4f*)(rp);
      const v4f t1 = *(const v4f*)(rp + 4);
      const v4f t2 = *(const v4f*)(rp + 8);
      const v4f t3 = *(const v4f*)(rp + 12);
      float rb[18];
#pragma unroll
      for (int q = 0; q < 4; ++q) { rb[q] = t0[q]; rb[4+q] = t1[q]; rb[8+q] = t2[q]; rb[12+q] = t3[q]; }
      rb[16] = rp[16]; rb[17] = rp[17];
      const float w0 = wsm[c * 9 + dy * 3 + 0];
      const float w1 = wsm[c * 9 + dy * 3 + 1];
      const float w2 = wsm[c * 9 + dy * 3 + 2];
#pragma unroll
      for (int j = 0; j < 16; ++j)
        o[j] += w0 * rb[j] + w1 * rb[j + 1] + w2 * rb[j + 2];
    }
  };

  float qreg[16], kreg[16];
  v4f sbuf[6];

  stage_load(0, sbuf);
  stage_write(0, sbuf);
  __syncthreads();
  v4f sk[6];
  stage_load(1, sk);           // k-loads in flight under conv(q)
  conv16(qreg);
  {
    float s = 0.f;
#pragma unroll
    for (int j = 0; j < 16; ++j) s += qreg[j] * qreg[j];
    s += __shfl_xor(s, 16, 64);
    s += __shfl_xor(s, 32, 64);
    if (lane < 16) redQ[w4 * 16 + lane] = s;
  }
  __syncthreads();             // halo q reads done
  stage_write(1, sk);
  __syncthreads();
  v4f sv[6];
  stage_load(2, sv);           // v-loads in flight under conv(k)+gram
  conv16(kreg);
  {
    float s = 0.f;
#pragma unroll
    for (int j = 0; j < 16; ++j) s += kreg[j] * kreg[j];
    s += __shfl_xor(s, 16, 64);
    s += __shfl_xor(s, 32, 64);
    if (lane < 16) redK[w4 * 16 + lane] = s;
  }
  { // gram: wave covers px [64*w4, 64*w4+64); trunc-split + cvt_pk, split-bf16 MFMA
    v4f acc = {0.f, 0.f, 0.f, 0.f};
    const int qt = lane >> 4;
    const bool hiHalf = (qt & 1);
#pragma unroll
    for (int f = 0; f < 2; ++f) {
      const int src = ((f * 2 + (qt >> 1)) << 4) | (lane & 15);
      v4u qh4, ql4, kh4, kl4;
#pragma unroll
      for (int jj = 0; jj < 4; ++jj) {
        const float q0a = __shfl(qreg[2 * jj], src, 64);
        const float q0b = __shfl(qreg[2 * jj + 8], src, 64);
        const float q1a = __shfl(qreg[2 * jj + 1], src, 64);
        const float q1b = __shfl(qreg[2 * jj + 9], src, 64);
        const float k0a = __shfl(kreg[2 * jj], src, 64);
        const float k0b = __shfl(kreg[2 * jj + 8], src, 64);
        const float k1a = __shfl(kreg[2 * jj + 1], src, 64);
        const float k1b = __shfl(kreg[2 * jj + 9], src, 64);
        const float q0 = hiHalf ? q0b : q0a, q1 = hiHalf ? q1b : q1a;
        const float k0 = hiHalf ? k0b : k0a, k1 = hiHalf ? k1b : k1a;
        const u2 tq = split2pk(q0, q1); qh4[jj] = tq.h; ql4[jj] = tq.l;
        const u2 tk = split2pk(k0, k1); kh4[jj] = tk.h; kl4[jj] = tk.l;
      }
      const v8s qh = __builtin_bit_cast(v8s, qh4);
      const v8s ql = __builtin_bit_cast(v8s, ql4);
      const v8s kh = __builtin_bit_cast(v8s, kh4);
      const v8s kl = __builtin_bit_cast(v8s, kl4);
      acc = mfma16(qh, kh, acc);
      acc = mfma16(ql, kh, acc);
      acc = mfma16(qh, kl, acc);
      acc = mfma16(ql, kl, acc);
    }
#pragma unroll
    for (int rr = 0; rr < 4; ++rr)
      gramW[w4 * 256 + (qt * 4 + rr) * 16 + (lane & 15)] = acc[rr];
  }
  __syncthreads();             // halo k reads done; redQ/redK/gramW visible
  stage_write(2, sv);
  __syncthreads();
  float vv[16];
  conv16(vv);
  if (tid < 16) {
    const float t = redQ[tid] + redQ[16 + tid] + redQ[32 + tid] + redQ[48 + tid];
    atomicAdd(&qn[b * 128 + h * 16 + tid], (double)t);
  } else if (tid < 32) {
    const int cc = tid - 16;
    const float t = redK[cc] + redK[16 + cc] + redK[32 + cc] + redK[48 + cc];
    atomicAdd(&kn[b * 128 + h * 16 + cc], (double)t);
  }
  {
    const float g = gramW[tid] + gramW[256 + tid] + gramW[512 + tid] + gramW[768 + tid];
    atomicAdd(&gram[(size_t)(b * 8 + h) * 256 + tid], (double)g);
  }
  __syncthreads();             // all halo reads done before alias write
  {
#pragma unroll
    for (int j = 0; j < 16; ++j) vtr[(r * 16 + j) * 24 + c] = f2bf(vv[j]);
  }
  __syncthreads();
  {
    const v8s o0 = *(const v8s*)(vtr + tid * 24);
    const v8s o1 = *(const v8s*)(vtr + tid * 24 + 8);
    short* dst = vbuf + ((size_t)b * 65536 + (size_t)(py0 + (tid >> 4)) * 256 + (px0 + (tid & 15))) * 128 + h * 16;
    *(v8s*)dst = o0;
    *(v8s*)(dst + 8) = o1;
  }
}

// K3a: normalize gram -> cosine attn, temperature, dyn_k top-k mask, softmax, *sum(attn1..4)
__global__ void k3a_attn(const double* __restrict__ gram, const double* __restrict__ qn,
                         const double* __restrict__ kn, const double* __restrict__ gsum,
                         const float* __restrict__ temp,
                         const float* __restrict__ a1p, const float* __restrict__ a2p,
                         const float* __restrict__ a3p, const float* __restrict__ a4p,
                         float* __restrict__ attnw) {
  const int t = threadIdx.x;  // 256 rows: (b,h,c)
  const int b = t >> 7, rem = t & 127, h = rem >> 4, c = rem & 15;
  const float qnv = fmaxf(sqrtf((float)qn[b * 128 + h * 16 + c]), 1e-12f);
  const float tv = temp[h];
  float a[16];
#pragma unroll
  for (int d = 0; d < 16; ++d) {
    const float knv = fmaxf(sqrtf((float)kn[b * 128 + h * 16 + d]), 1e-12f);
    a[d] = (float)gram[(size_t)(b * 8 + h) * 256 + c * 16 + d] / (qnv * knv) * tv;
  }
  const float dynk = floorf(16.f * (float)(gsum[0] / 131072.0));
  float mx = -INFINITY;
  bool keep[16];
#pragma unroll
  for (int d = 0; d < 16; ++d) {
    int rank = 0;
#pragma unroll
    for (int e = 0; e < 16; ++e)
      rank += ((a[e] > a[d]) || ((a[e] == a[d]) && (e < d))) ? 1 : 0;
    keep[d] = ((float)rank < dynk);
    if (keep[d]) mx = fmaxf(mx, a[d]);
  }
  float ssum = 0.f, wvv[16];
#pragma unroll
  for (int d = 0; d < 16; ++d) {
    wvv[d] = keep[d] ? expf(a[d] - mx) : 0.f;
    ssum += wvv[d];
  }
  const float satt = a1p[0] + a2p[0] + a3p[0] + a4p[0];
  const float sc = satt / ssum;
#pragma unroll
  for (int d = 0; d < 16; ++d) attnw[t * 16 + d] = wvv[d] * sc;
}

// K3b: fold attention into projection, FRAGMENT-MAJOR bf16 out
__global__ void k3b_fold(const float* __restrict__ proj_w, const float* __restrict__ attnw,
                         short* __restrict__ W2f) {
  const int g = blockIdx.x, b = blockIdx.y;
  const int ks = threadIdx.x >> 6, lane = threadIdx.x & 63;
  const int o = g * 16 + (lane & 15);
  const int k0 = ks * 32 + (lane >> 4) * 8;
  v8s outv;
  if (k0 < 128) {
    const int h = k0 >> 4, d0 = k0 & 15;
    float s[8];
#pragma unroll
    for (int j = 0; j < 8; ++j) s[j] = 0.f;
#pragma unroll
    for (int i = 0; i < 16; ++i) {
      const float pw = proj_w[o * 256 + h * 16 + i];
#pragma unroll
      for (int j = 0; j < 8; ++j)
        s[j] += pw * attnw[((b * 8 + h) * 16 + i) * 16 + d0 + j];
    }
#pragma unroll
    for (int j = 0; j < 8; ++j) outv[j] = f2bf(s[j]);
  } else {
#pragma unroll
    for (int j = 0; j < 8; ++j) outv[j] = f2bf(proj_w[o * 256 + k0 + j]);
  }
  *(v8s*)(W2f + ((size_t)(b * 128 + g * 8 + ks) * 64 + lane) * 8) = outv;
}

// K4: out[m][o] = [v(m);x2(m)] @ W2[b]^T (M=131072,K=256,N=256). Fragment-major B pipeline.
__global__ __launch_bounds__(512, 4) void k4_out(const short* __restrict__ vbuf,
                                                 const float* __restrict__ x,
                                                 const short* __restrict__ W2f,
                                                 float* __restrict__ out) {
  __shared__ __align__(16) unsigned char sm[32768];
  const int tid = threadIdx.x;
  const size_t m0 = (size_t)blockIdx.x * 64;
  const int b = (int)(m0 >> 16);
  const int lane = tid & 63, wid = tid >> 6;
  const int wm = wid >> 2, wn = wid & 3;

  v8s pbB[3];
#pragma unroll
  for (int s = 0; s < 3; ++s) {
    const size_t off = ((size_t)(b * 128 + (0 * 4 + wn) * 8 + s) * 64 + lane) * 8;
    pbB[s] = *(const v8s*)(W2f + off);
  }
  {
    const int row = tid >> 3, c0 = (tid & 7) * 16;
    {
      const short* src = vbuf + (m0 + (size_t)row) * 128 + c0;
#pragma unroll
      for (int half = 0; half < 2; ++half) {
        const int col = c0 + half * 8;
        const int byo = (row * 512 + col * 2) ^ ((row & 7) << 4);
        *(v8s*)(sm + byo) = *(const v8s*)(src + half * 8);
      }
    }
    {
      const float* src = x + (m0 + (size_t)row) * 256 + 128 + c0;
#pragma unroll
      for (int half = 0; half < 2; ++half) {
        v4f f0 = *(const v4f*)(src + half * 8);
        v4f f1 = *(const v4f*)(src + half * 8 + 4);
        v4u hv;
        hv[0] = pack_rn(f0[0], f0[1]); hv[1] = pack_rn(f0[2], f0[3]);
        hv[2] = pack_rn(f1[0], f1[1]); hv[3] = pack_rn(f1[2], f1[3]);
        const int col = 128 + c0 + half * 8;
        const int byo = (row * 512 + col * 2) ^ ((row & 7) << 4);
        *(v4u*)(sm + byo) = hv;
      }
    }
  }
  __syncthreads();
  v8s af[8][2];
#pragma unroll
  for (int ks = 0; ks < 8; ++ks)
#pragma unroll
    for (int mi = 0; mi < 2; ++mi) {
      const int kb2 = (ks * 32 + ((lane >> 4) * 8)) * 2;
      const int m = wm * 32 + mi * 16 + (lane & 15);
      const int byoA = (m * 512 + kb2) ^ ((m & 7) << 4);
      af[ks][mi] = *(const v8s*)(sm + byoA);
    }
  const v4f vz = {0.f, 0.f, 0.f, 0.f};
  v4f acc[4][2];
#pragma unroll
  for (int i = 0; i < 4; ++i) { acc[i][0] = vz; acc[i][1] = vz; }
#pragma unroll
  for (int s = 0; s < 32; ++s) {
    const int nc = s >> 3, ks = s & 7, slot = s % 3;
    const v8s bf = pbB[slot];
    if (s + 3 < 32) {
      const int s3 = s + 3, nc3 = s3 >> 3, ks3 = s3 & 7;
      const size_t off = ((size_t)(b * 128 + (nc3 * 4 + wn) * 8 + ks3) * 64 + lane) * 8;
      pbB[slot] = *(const v8s*)(W2f + off);
    }
#pragma unroll
    for (int mi = 0; mi < 2; ++mi)
      acc[nc][mi] = mfma16(af[ks][mi], bf, acc[nc][mi]);
  }
#pragma unroll
  for (int nc = 0; nc < 4; ++nc)
#pragma unroll
    for (int mi = 0; mi < 2; ++mi)
#pragma unroll
      for (int r = 0; r < 4; ++r) {
        const int m = wm * 32 + mi * 16 + ((lane >> 4) * 4) + r;
        const int o = nc * 64 + wn * 16 + (lane & 15);
        out[(m0 + m) * 256 + o] = acc[nc][mi][r];
      }
}

extern "C" void kernel_launch(void* const* d_in, const int* in_sizes, int n_in,
                              void* d_out, int out_size, void* d_ws, size_t ws_size,
                              hipStream_t stream) {
  const float* x      = (const float*)d_in[0];
  const float* qkv_w  = (const float*)d_in[1];
  const float* dw_w   = (const float*)d_in[2];
  const float* proj_w = (const float*)d_in[3];
  const float* g1_w   = (const float*)d_in[4];
  const float* g1_b   = (const float*)d_in[5];
  const float* g2_w   = (const float*)d_in[6];
  const float* g2_b   = (const float*)d_in[7];
  const float* temp   = (const float*)d_in[8];
  const float* a1     = (const float*)d_in[9];
  const float* a2     = (const float*)d_in[10];
  const float* a3     = (const float*)d_in[11];
  const float* a4     = (const float*)d_in[12];
  float* out = (float*)d_out;
  char* ws = (char*)d_ws;

  double* gram  = (double*)(ws + OFF_GRAM);
  double* qn    = (double*)(ws + OFF_QN);
  double* kn    = (double*)(ws + OFF_KN);
  double* gsum  = (double*)(ws + OFF_GSUM);
  float*  attnw = (float*)(ws + OFF_ATTN);
  short*  wqh   = (short*)(ws + OFF_WQH);
  short*  wql   = (short*)(ws + OFF_WQL);
  short*  g1h   = (short*)(ws + OFF_G1H);
  short*  g1l   = (short*)(ws + OFF_G1L);
  short*  W2f   = (short*)(ws + OFF_W2);
  float*  qkf   = (float*)(ws + OFF_QK);
  short*  vb    = (short*)(ws + OFF_V);
  short*  vbuf  = (short*)(ws + OFF_VOUT);

  hipMemsetAsync(ws, 0, 40960, stream);                       // gram/qn/kn/gsum accumulators
  k0_split<<<40, 256, 0, stream>>>(qkv_w, g1_w, wqh, wql, g1h, g1l);
  k1_qkv<<<2048, 512, 0, stream>>>(x, wqh, wql, qkf, vb);
  k1_g<<<2048, 512, 0, stream>>>(x, g1h, g1l, g1_b, g2_w, g2_b, gsum);
  k2_conv<<<dim3(256, 8, 2), 256, 0, stream>>>(qkf, vb, dw_w, gram, qn, kn, vbuf);
  k3a_attn<<<1, 256, 0, stream>>>(gram, qn, kn, gsum, temp, a1, a2, a3, a4, attnw);
  k3b_fold<<<dim3(16, 2), 512, 0, stream>>>(proj_w, attnw, W2f);
  k4_out<<<2048, 512, 0, stream>>>(vbuf, x, W2f, out);
  (void)in_sizes; (void)n_in; (void)out_size; (void)ws_size;
}

// Round 7
// 257.769 us; speedup vs baseline: 1.4999x; 1.0867x over previous
//
#include <hip/hip_runtime.h>
#include <hip/hip_bf16.h>
#include <cstdint>
#include <cstddef>

typedef __attribute__((ext_vector_type(4))) float v4f;
typedef __attribute__((ext_vector_type(8))) short v8s;
typedef __attribute__((ext_vector_type(4))) short v4s;
typedef __attribute__((ext_vector_type(4))) unsigned v4u;

__device__ __forceinline__ short f2bf(float f) {
  unsigned u = __float_as_uint(f);
  u += 0x7FFFu + ((u >> 16) & 1u);   // round-to-nearest-even
  return (short)(u >> 16);
}
__device__ __forceinline__ float bf2f(short h) {
  return __uint_as_float(((unsigned)(unsigned short)h) << 16);
}
__device__ __forceinline__ v4f mfma16(v8s a, v8s b, v4f c) {
  return __builtin_amdgcn_mfma_f32_16x16x32_bf16(a, b, c, 0, 0, 0);
}
// packed RNE f32x2 -> bf16x2 (low word = a)
__device__ __forceinline__ unsigned pack_rn(float a, float b) {
  __hip_bfloat162 p = __float22bfloat162_rn(make_float2(a, b));
  union { __hip_bfloat162 v; unsigned u; } c; c.v = p; return c.u;
}
// trunc-hi split of a pair: a=hi+lo (hi exact bf16 via truncation, lo RNE bf16)
struct u2 { unsigned h, l; };
__device__ __forceinline__ u2 split2pk(float a, float b) {
  const unsigned ua = __float_as_uint(a) & 0xffff0000u;
  const unsigned ub = __float_as_uint(b) & 0xffff0000u;
  const float la = a - __uint_as_float(ua);
  const float lb = b - __uint_as_float(ub);
  u2 r;
  r.h = (ua >> 16) | ub;
  r.l = pack_rn(la, lb);
  return r;
}

// ---------------- workspace layout (bytes) ----------------
#define OFF_GRAM   0u          // double[2*8*16*16] = 32768
#define OFF_QN     32768u      // double[256]
#define OFF_KN     34816u      // double[256]
#define OFF_GSUM   36864u      // double[1]
#define OFF_ATTN   40960u      // float[4096]
#define OFF_WQH    65536u      // short[6144*8] fragment-major qkv hi
#define OFF_WQL    163840u     // lo
#define OFF_G1H    262144u     // short[4096*8] fragment-major g1 hi
#define OFF_G1L    327680u
#define OFF_W2     393216u     // short[2*128*64*8] = 512KB fragment-major folded proj
#define OFF_QK     1048576u    // float[131072*256] pixel-major (q ch 0..127, k ch 128..255)
#define OFF_V      135266304u  // short[131072*128] pixel-major bf16 (raw v)
#define OFF_VOUT   168820736u  // short[131072*128] post-conv v

// K0: split fp32 weights into bf16 hi/lo planes (RNE), FRAGMENT-MAJOR
__global__ void k0_split(const float* __restrict__ qkv_w, const float* __restrict__ g1_w,
                         short* __restrict__ wqh, short* __restrict__ wql,
                         short* __restrict__ g1h, short* __restrict__ g1l) {
  const int t = blockIdx.x * 256 + threadIdx.x;
  if (t < 6144) {
    const int l = t & 63, ks = (t >> 6) & 3, g = t >> 8;
    const int n = g * 16 + (l & 15), k = ks * 32 + (l >> 4) * 8;
    v8s hi, lo;
#pragma unroll
    for (int j = 0; j < 8; ++j) {
      const float f = qkv_w[n * 128 + k + j];
      const short h = f2bf(f);
      hi[j] = h; lo[j] = f2bf(f - bf2f(h));
    }
    *(v8s*)(wqh + (size_t)t * 8) = hi;
    *(v8s*)(wql + (size_t)t * 8) = lo;
  } else if (t < 10240) {
    const int t2 = t - 6144;
    const int l = t2 & 63, ks2 = (t2 >> 6) & 7, g2 = t2 >> 9;
    const int n = g2 * 16 + (l & 15), k = ks2 * 32 + (l >> 4) * 8;
    v8s hi, lo;
#pragma unroll
    for (int j = 0; j < 8; ++j) {
      const float f = g1_w[n * 256 + k + j];
      const short h = f2bf(f);
      hi[j] = h; lo[j] = f2bf(f - bf2f(h));
    }
    *(v8s*)(g1h + (size_t)t2 * 8) = hi;
    *(v8s*)(g1l + (size_t)t2 * 8) = lo;
  }
}

// K1f: FUSED qkv-GEMM + gate-GEMM. One read of x, shared A staging/split.
// Phase 1: A = x cols 0..127 -> g kc=0 (8 steps, 4-term) + qkv (24 steps; q,k 3-term, v 1-term),
//          early-retiring each acc[nc] (8 live acc VGPRs).
// Phase 2: A = x cols 128..255 -> g kc=1 (8 steps), then g epilogue (sigmoid+mean),
//          then coalesced v store via vtr.
__global__ __launch_bounds__(512, 4) void k1f(const float* __restrict__ x,
                                              const short* __restrict__ wqh,
                                              const short* __restrict__ wql,
                                              const short* __restrict__ g1h,
                                              const short* __restrict__ g1l,
                                              const float* __restrict__ g1_b,
                                              const float* __restrict__ g2_w,
                                              const float* __restrict__ g2_b,
                                              float* __restrict__ qkf,
                                              short* __restrict__ vb,
                                              double* __restrict__ gsum) {
  __shared__ __align__(16) unsigned char sm[49152]; // Ah@0 Al@16384 vtr@32768
  const int tid = threadIdx.x;
  const size_t m0 = (size_t)blockIdx.x * 64;
  const int lane = tid & 63, wid = tid >> 6;
  const int wm = wid >> 2, wn = wid & 3;
  short* vtr = (short*)(sm + 32768);

  // unified phase-1 step s in [0,32): s<8 -> g kc=0 (nc=s>>2, ks=s&3); s>=8 -> qkv t=s-8
  auto bh_ptr = [&](int s) -> const short* {
    if (s < 8) { const int nc = s >> 2, ks = s & 3;
      return g1h + ((size_t)((nc * 4 + wn) * 8 + ks) * 64 + lane) * 8; }
    const int t = s - 8, nc = t >> 2, ks = t & 3;
    return wqh + ((size_t)((nc * 4 + wn) * 4 + ks) * 64 + lane) * 8;
  };
  auto bl_ptr = [&](int s) -> const short* {
    if (s < 8) { const int nc = s >> 2, ks = s & 3;
      return g1l + ((size_t)((nc * 4 + wn) * 8 + ks) * 64 + lane) * 8; }
    const int t = s - 8, nc = t >> 2, ks = t & 3;
    return wql + ((size_t)((nc * 4 + wn) * 4 + ks) * 64 + lane) * 8;
  };

  // B pipeline prologue (steps 0..2 are g-steps, need hi+lo)
  v8s pbh[3], pbl[3];
#pragma unroll
  for (int s = 0; s < 3; ++s) {
    pbh[s] = *(const v8s*)bh_ptr(s);
    pbl[s] = *(const v8s*)bl_ptr(s);
  }

  { // stage A1 = x cols 0..127 (trunc-hi split, packed, swizzled)
    const int row = tid >> 3, c0 = (tid & 7) * 16;
    const float* src = x + (m0 + (size_t)row) * 256 + c0;
#pragma unroll
    for (int half = 0; half < 2; ++half) {
      v4f f0 = *(const v4f*)(src + half * 8);
      v4f f1 = *(const v4f*)(src + half * 8 + 4);
      v4u hi, lo;
      u2 t0 = split2pk(f0[0], f0[1]); hi[0] = t0.h; lo[0] = t0.l;
      u2 t1 = split2pk(f0[2], f0[3]); hi[1] = t1.h; lo[1] = t1.l;
      u2 t2 = split2pk(f1[0], f1[1]); hi[2] = t2.h; lo[2] = t2.l;
      u2 t3 = split2pk(f1[2], f1[3]); hi[3] = t3.h; lo[3] = t3.l;
      const int col = c0 + half * 8;
      const int byo = (row * 256 + col * 2) ^ ((row & 7) << 4);
      *(v4u*)(sm + byo) = hi;
      *(v4u*)(sm + 16384 + byo) = lo;
    }
  }
  __syncthreads();
  v8s ah[4][2];
#pragma unroll
  for (int ks = 0; ks < 4; ++ks)
#pragma unroll
    for (int mi = 0; mi < 2; ++mi) {
      const int kb2 = (ks * 32 + ((lane >> 4) * 8)) * 2;
      const int m = wm * 32 + mi * 16 + (lane & 15);
      const int byoA = (m * 256 + kb2) ^ ((m & 7) << 4);
      ah[ks][mi] = *(const v8s*)(sm + byoA);
    }
  const v4f vz = {0.f, 0.f, 0.f, 0.f};
  v4f accg[2][2];
  accg[0][0] = vz; accg[0][1] = vz; accg[1][0] = vz; accg[1][1] = vz;
  v4f accq[2];

#pragma unroll
  for (int s = 0; s < 32; ++s) {
    const int slot = s % 3;
    const v8s bh = pbh[slot];
    const v8s bl = pbl[slot];
    if (s + 3 < 32) {
      const int s3 = s + 3;
      pbh[slot] = *(const v8s*)bh_ptr(s3);
      const bool needl = (s3 < 8) || (s3 - 8 < 16);
      if (needl) pbl[slot] = *(const v8s*)bl_ptr(s3);
    }
    if (s < 8) { // gate step (kc=0), 4-term
      const int nc = s >> 2, ks = s & 3;
#pragma unroll
      for (int mi = 0; mi < 2; ++mi) {
        const int kb2 = (ks * 32 + ((lane >> 4) * 8)) * 2;
        const int m = wm * 32 + mi * 16 + (lane & 15);
        const int byoA = (m * 256 + kb2) ^ ((m & 7) << 4);
        const v8s alv = *(const v8s*)(sm + 16384 + byoA);
        accg[nc][mi] = mfma16(ah[ks][mi], bh, accg[nc][mi]);
        accg[nc][mi] = mfma16(alv, bh, accg[nc][mi]);
        accg[nc][mi] = mfma16(ah[ks][mi], bl, accg[nc][mi]);
        accg[nc][mi] = mfma16(alv, bl, accg[nc][mi]);
      }
    } else {     // qkv step; early retire at ks==3
      const int t = s - 8, nc = t >> 2, ks = t & 3;
#pragma unroll
      for (int mi = 0; mi < 2; ++mi) {
        if (ks == 0) accq[mi] = vz;
        const int kb2 = (ks * 32 + ((lane >> 4) * 8)) * 2;
        const int m = wm * 32 + mi * 16 + (lane & 15);
        const int byoA = (m * 256 + kb2) ^ ((m & 7) << 4);
        accq[mi] = mfma16(ah[ks][mi], bh, accq[mi]);
        if (nc < 4) {
          const v8s alv = *(const v8s*)(sm + 16384 + byoA);
          accq[mi] = mfma16(alv, bh, accq[mi]);
          accq[mi] = mfma16(ah[ks][mi], bl, accq[mi]);
        }
      }
      if (ks == 3) {
        if (nc < 4) { // q,k -> fp32 global (scattered, r3-proven ok)
#pragma unroll
          for (int mi = 0; mi < 2; ++mi)
#pragma unroll
            for (int r = 0; r < 4; ++r) {
              const int m = wm * 32 + mi * 16 + ((lane >> 4) * 4) + r;
              const int n = nc * 64 + wn * 16 + (lane & 15);
              qkf[(m0 + m) * 256 + n] = accq[mi][r];
            }
        } else {      // v -> bf16 vtr (LDS)
#pragma unroll
          for (int mi = 0; mi < 2; ++mi)
#pragma unroll
            for (int r = 0; r < 4; ++r) {
              const int m = wm * 32 + mi * 16 + ((lane >> 4) * 4) + r;
              const int n = (nc - 4) * 64 + wn * 16 + (lane & 15);
              vtr[m * 128 + n] = f2bf(accq[mi][r]);
            }
        }
      }
    }
  }

  // ---- phase 2: gate kc=1 ----
  v8s pb2h[3], pb2l[3];
#pragma unroll
  for (int s = 0; s < 3; ++s) { // nc=0, ks=s, kc=1
    const size_t off = ((size_t)((0 * 4 + wn) * 8 + 4 + s) * 64 + lane) * 8;
    pb2h[s] = *(const v8s*)(g1h + off);
    pb2l[s] = *(const v8s*)(g1l + off);
  }
  __syncthreads();   // all A1 reads done
  { // stage A2 = x cols 128..255
    const int row = tid >> 3, c0 = (tid & 7) * 16;
    const float* src = x + (m0 + (size_t)row) * 256 + 128 + c0;
#pragma unroll
    for (int half = 0; half < 2; ++half) {
      v4f f0 = *(const v4f*)(src + half * 8);
      v4f f1 = *(const v4f*)(src + half * 8 + 4);
      v4u hi, lo;
      u2 t0 = split2pk(f0[0], f0[1]); hi[0] = t0.h; lo[0] = t0.l;
      u2 t1 = split2pk(f0[2], f0[3]); hi[1] = t1.h; lo[1] = t1.l;
      u2 t2 = split2pk(f1[0], f1[1]); hi[2] = t2.h; lo[2] = t2.l;
      u2 t3 = split2pk(f1[2], f1[3]); hi[3] = t3.h; lo[3] = t3.l;
      const int col = c0 + half * 8;
      const int byo = (row * 256 + col * 2) ^ ((row & 7) << 4);
      *(v4u*)(sm + byo) = hi;
      *(v4u*)(sm + 16384 + byo) = lo;
    }
  }
  __syncthreads();
#pragma unroll
  for (int s = 0; s < 8; ++s) {
    const int nc = s >> 2, ks = s & 3, slot = s % 3;
    const v8s bh = pb2h[slot];
    const v8s bl = pb2l[slot];
    if (s + 3 < 8) {
      const int s3 = s + 3, nc3 = s3 >> 2, ks3 = s3 & 3;
      const size_t off = ((size_t)((nc3 * 4 + wn) * 8 + 4 + ks3) * 64 + lane) * 8;
      pb2h[slot] = *(const v8s*)(g1h + off);
      pb2l[slot] = *(const v8s*)(g1l + off);
    }
#pragma unroll
    for (int mi = 0; mi < 2; ++mi) {
      const int kb2 = (ks * 32 + ((lane >> 4) * 8)) * 2;
      const int m = wm * 32 + mi * 16 + (lane & 15);
      const int byoA = (m * 256 + kb2) ^ ((m & 7) << 4);
      const v8s alv = *(const v8s*)(sm + 16384 + byoA);
      accg[nc][mi] = mfma16(ah[ks][mi], bh, accg[nc][mi]);
      accg[nc][mi] = mfma16(alv, bh, accg[nc][mi]);
      accg[nc][mi] = mfma16(ah[ks][mi], bl, accg[nc][mi]);
      accg[nc][mi] = mfma16(alv, bl, accg[nc][mi]);
    }
  }
  // gate epilogue: per-pixel g2 dot + sigmoid + block sum -> double atomic
  __syncthreads();                 // A region dead; reuse for g2ws/ldsg (vtr untouched)
  float* g2ws = (float*)sm;
  float* ldsg = (float*)(sm + 512);
  if (tid < 128) g2ws[tid] = g2_w[tid];
  if (tid < 64) ldsg[tid] = 0.f;
  __syncthreads();
  float bias[2], g2v[2];
#pragma unroll
  for (int nc = 0; nc < 2; ++nc) {
    const int n = nc * 64 + wn * 16 + (lane & 15);
    bias[nc] = g1_b[n];
    g2v[nc] = g2ws[n];
  }
#pragma unroll
  for (int mi = 0; mi < 2; ++mi)
#pragma unroll
    for (int r = 0; r < 4; ++r) {
      float part = 0.f;
#pragma unroll
      for (int nc = 0; nc < 2; ++nc) {
        float val = accg[nc][mi][r] + bias[nc];
        val = fmaxf(val, 0.f);
        part += val * g2v[nc];
      }
      part += __shfl_xor(part, 1, 16);
      part += __shfl_xor(part, 2, 16);
      part += __shfl_xor(part, 4, 16);
      part += __shfl_xor(part, 8, 16);
      if ((lane & 15) == 0)
        atomicAdd(&ldsg[wm * 32 + mi * 16 + ((lane >> 4) * 4) + r], part);
    }
  __syncthreads();
  if (tid < 64) {
    float pre = ldsg[tid] + g2_b[0];
    float g = 1.f / (1.f + expf(-pre));
#pragma unroll
    for (int mk = 1; mk < 64; mk <<= 1) g += __shfl_xor(g, mk, 64);
    if (tid == 0) atomicAdd(gsum, (double)g);
  }
  // coalesced v store (vtr complete since phase 1; barriers above ordered it)
  {
    const int base = tid * 8;
#pragma unroll
    for (int p = 0; p < 2; ++p) {
      const int flat = p * 4096 + base;
      const int row = flat >> 7, col = flat & 127;
      const v8s t = *(const v8s*)(vtr + row * 128 + col);
      *(v8s*)(vb + (m0 + row) * 128 + col) = t;
    }
  }
}

// K2: thread = (channel, row). Fused dwconv + norms + gram + v write. (unchanged from r6)
__global__ __launch_bounds__(256, 4) void k2_conv(const float* __restrict__ qkf,
                                                  const short* __restrict__ vb,
                                                  const float* __restrict__ dw_w,
                                                  double* __restrict__ gram,
                                                  double* __restrict__ qn,
                                                  double* __restrict__ kn,
                                                  short* __restrict__ vbuf) {
  __shared__ __align__(16) unsigned char SM[28480];
  float* haloT = (float*)SM;                 // [16 c][18 row][20 col] stride 364
  short* vtr   = (short*)SM;                 // alias, [px][24]
  float* wsm   = (float*)(SM + 23296);       // [16][9]
  float* redQ  = (float*)(SM + 23872);       // [wave][16]
  float* redK  = (float*)(SM + 24128);
  float* gramW = (float*)(SM + 24384);       // [wave][256]

  const int tid = threadIdx.x;
  const int tile = blockIdx.x, h = blockIdx.y, b = blockIdx.z;
  const int px0 = (tile & 15) * 16, py0 = (tile >> 4) * 16;
  const int c = tid & 15, r = tid >> 4;
  const int lane = tid & 63, w4 = tid >> 6;

  auto stage_load = [&](int sec, v4f* vals) {
    const int chbase = sec * 128 + h * 16;
#pragma unroll
    for (int i = 0; i < 6; ++i) {
      const int idx = tid + i * 256;
      v4f val = {0.f, 0.f, 0.f, 0.f};
      if (idx < 1296) {
        const int p = idx >> 2, e4 = (idx & 3) * 4;
        const int row = p / 18, col = p - row * 18;
        const int gy = py0 - 1 + row, gx = px0 - 1 + col;
        if (gy >= 0 && gy < 256 && gx >= 0 && gx < 256) {
          const size_t pix = (size_t)(b * 65536 + gy * 256 + gx);
          if (sec < 2) {
            val = *(const v4f*)(qkf + pix * 256 + sec * 128 + h * 16 + e4);
          } else {
            const v4s sv = *(const v4s*)(vb + pix * 128 + h * 16 + e4);
            val[0] = bf2f(sv[0]); val[1] = bf2f(sv[1]);
            val[2] = bf2f(sv[2]); val[3] = bf2f(sv[3]);
          }
        }
      }
      vals[i] = val;
    }
  };
  auto stage_write = [&](int sec, const v4f* vals) {
#pragma unroll
    for (int i = 0; i < 6; ++i) {
      const int idx = tid + i * 256;
      if (idx < 1296) {
        const int p = idx >> 2, e4 = (idx & 3) * 4;
        const int row = p / 18, col = p - row * 18;
        haloT[(e4 + 0) * 364 + row * 20 + col] = vals[i][0];
        haloT[(e4 + 1) * 364 + row * 20 + col] = vals[i][1];
        haloT[(e4 + 2) * 364 + row * 20 + col] = vals[i][2];
        haloT[(e4 + 3) * 364 + row * 20 + col] = vals[i][3];
      }
    }
    if (tid < 144) wsm[tid] = dw_w[(sec * 128 + h * 16) * 9 + tid];
  };

  auto conv16 = [&](float* o) {
#pragma unroll
    for (int j = 0; j < 16; ++j) o[j] = 0.f;
#pragma unroll
    for (int dy = 0; dy < 3; ++dy) {
      const float* rp = haloT + c * 364 + (r + dy) * 20;
      const v4f t0 = *(const v4f*)(rp);
      const v4f t1 = *(const v4f*)(rp + 4);
      const v4f t2 = *(const v4f*)(rp + 8);
      const v4f t3 = *(const v4f*)(rp + 12);
      float rb[18];
#pragma unroll
      for (int q = 0; q < 4; ++q) { rb[q] = t0[q]; rb[4+q] = t1[q]; rb[8+q] = t2[q]; rb[12+q] = t3[q]; }
      rb[16] = rp[16]; rb[17] = rp[17];
      const float w0 = wsm[c * 9 + dy * 3 + 0];
      const float w1 = wsm[c * 9 + dy * 3 + 1];
      const float w2 = wsm[c * 9 + dy * 3 + 2];
#pragma unroll
      for (int j = 0; j < 16; ++j)
        o[j] += w0 * rb[j] + w1 * rb[j + 1] + w2 * rb[j + 2];
    }
  };

  float qreg[16], kreg[16];
  v4f sbuf[6];

  stage_load(0, sbuf);
  stage_write(0, sbuf);
  __syncthreads();
  v4f sk[6];
  stage_load(1, sk);
  conv16(qreg);
  {
    float s = 0.f;
#pragma unroll
    for (int j = 0; j < 16; ++j) s += qreg[j] * qreg[j];
    s += __shfl_xor(s, 16, 64);
    s += __shfl_xor(s, 32, 64);
    if (lane < 16) redQ[w4 * 16 + lane] = s;
  }
  __syncthreads();
  stage_write(1, sk);
  __syncthreads();
  v4f sv[6];
  stage_load(2, sv);
  conv16(kreg);
  {
    float s = 0.f;
#pragma unroll
    for (int j = 0; j < 16; ++j) s += kreg[j] * kreg[j];
    s += __shfl_xor(s, 16, 64);
    s += __shfl_xor(s, 32, 64);
    if (lane < 16) redK[w4 * 16 + lane] = s;
  }
  {
    v4f acc = {0.f, 0.f, 0.f, 0.f};
    const int qt = lane >> 4;
    const bool hiHalf = (qt & 1);
#pragma unroll
    for (int f = 0; f < 2; ++f) {
      const int src = ((f * 2 + (qt >> 1)) << 4) | (lane & 15);
      v4u qh4, ql4, kh4, kl4;
#pragma unroll
      for (int jj = 0; jj < 4; ++jj) {
        const float q0a = __shfl(qreg[2 * jj], src, 64);
        const float q0b = __shfl(qreg[2 * jj + 8], src, 64);
        const float q1a = __shfl(qreg[2 * jj + 1], src, 64);
        const float q1b = __shfl(qreg[2 * jj + 9], src, 64);
        const float k0a = __shfl(kreg[2 * jj], src, 64);
        const float k0b = __shfl(kreg[2 * jj + 8], src, 64);
        const float k1a = __shfl(kreg[2 * jj + 1], src, 64);
        const float k1b = __shfl(kreg[2 * jj + 9], src, 64);
        const float q0 = hiHalf ? q0b : q0a, q1 = hiHalf ? q1b : q1a;
        const float k0 = hiHalf ? k0b : k0a, k1 = hiHalf ? k1b : k1a;
        const u2 tq = split2pk(q0, q1); qh4[jj] = tq.h; ql4[jj] = tq.l;
        const u2 tk = split2pk(k0, k1); kh4[jj] = tk.h; kl4[jj] = tk.l;
      }
      const v8s qh = __builtin_bit_cast(v8s, qh4);
      const v8s ql = __builtin_bit_cast(v8s, ql4);
      const v8s kh = __builtin_bit_cast(v8s, kh4);
      const v8s kl = __builtin_bit_cast(v8s, kl4);
      acc = mfma16(qh, kh, acc);
      acc = mfma16(ql, kh, acc);
      acc = mfma16(qh, kl, acc);
      acc = mfma16(ql, kl, acc);
    }
#pragma unroll
    for (int rr = 0; rr < 4; ++rr)
      gramW[w4 * 256 + (qt * 4 + rr) * 16 + (lane & 15)] = acc[rr];
  }
  __syncthreads();
  stage_write(2, sv);
  __syncthreads();
  float vv[16];
  conv16(vv);
  if (tid < 16) {
    const float t = redQ[tid] + redQ[16 + tid] + redQ[32 + tid] + redQ[48 + tid];
    atomicAdd(&qn[b * 128 + h * 16 + tid], (double)t);
  } else if (tid < 32) {
    const int cc = tid - 16;
    const float t = redK[cc] + redK[16 + cc] + redK[32 + cc] + redK[48 + cc];
    atomicAdd(&kn[b * 128 + h * 16 + cc], (double)t);
  }
  {
    const float g = gramW[tid] + gramW[256 + tid] + gramW[512 + tid] + gramW[768 + tid];
    atomicAdd(&gram[(size_t)(b * 8 + h) * 256 + tid], (double)g);
  }
  __syncthreads();
  {
#pragma unroll
    for (int j = 0; j < 16; ++j) vtr[(r * 16 + j) * 24 + c] = f2bf(vv[j]);
  }
  __syncthreads();
  {
    const v8s o0 = *(const v8s*)(vtr + tid * 24);
    const v8s o1 = *(const v8s*)(vtr + tid * 24 + 8);
    short* dst = vbuf + ((size_t)b * 65536 + (size_t)(py0 + (tid >> 4)) * 256 + (px0 + (tid & 15))) * 128 + h * 16;
    *(v8s*)dst = o0;
    *(v8s*)(dst + 8) = o1;
  }
}

// K3a: normalize gram -> cosine attn, temperature, dyn_k top-k mask, softmax, *sum(attn1..4)
__global__ void k3a_attn(const double* __restrict__ gram, const double* __restrict__ qn,
                         const double* __restrict__ kn, const double* __restrict__ gsum,
                         const float* __restrict__ temp,
                         const float* __restrict__ a1p, const float* __restrict__ a2p,
                         const float* __restrict__ a3p, const float* __restrict__ a4p,
                         float* __restrict__ attnw) {
  const int t = threadIdx.x;  // 256 rows: (b,h,c)
  const int b = t >> 7, rem = t & 127, h = rem >> 4, c = rem & 15;
  const float qnv = fmaxf(sqrtf((float)qn[b * 128 + h * 16 + c]), 1e-12f);
  const float tv = temp[h];
  float a[16];
#pragma unroll
  for (int d = 0; d < 16; ++d) {
    const float knv = fmaxf(sqrtf((float)kn[b * 128 + h * 16 + d]), 1e-12f);
    a[d] = (float)gram[(size_t)(b * 8 + h) * 256 + c * 16 + d] / (qnv * knv) * tv;
  }
  const float dynk = floorf(16.f * (float)(gsum[0] / 131072.0));
  float mx = -INFINITY;
  bool keep[16];
#pragma unroll
  for (int d = 0; d < 16; ++d) {
    int rank = 0;
#pragma unroll
    for (int e = 0; e < 16; ++e)
      rank += ((a[e] > a[d]) || ((a[e] == a[d]) && (e < d))) ? 1 : 0;
    keep[d] = ((float)rank < dynk);
    if (keep[d]) mx = fmaxf(mx, a[d]);
  }
  float ssum = 0.f, wvv[16];
#pragma unroll
  for (int d = 0; d < 16; ++d) {
    wvv[d] = keep[d] ? expf(a[d] - mx) : 0.f;
    ssum += wvv[d];
  }
  const float satt = a1p[0] + a2p[0] + a3p[0] + a4p[0];
  const float sc = satt / ssum;
#pragma unroll
  for (int d = 0; d < 16; ++d) attnw[t * 16 + d] = wvv[d] * sc;
}

// K3b: fold attention into projection, FRAGMENT-MAJOR bf16 out
__global__ void k3b_fold(const float* __restrict__ proj_w, const float* __restrict__ attnw,
                         short* __restrict__ W2f) {
  const int g = blockIdx.x, b = blockIdx.y;
  const int ks = threadIdx.x >> 6, lane = threadIdx.x & 63;
  const int o = g * 16 + (lane & 15);
  const int k0 = ks * 32 + (lane >> 4) * 8;
  v8s outv;
  if (k0 < 128) {
    const int h = k0 >> 4, d0 = k0 & 15;
    float s[8];
#pragma unroll
    for (int j = 0; j < 8; ++j) s[j] = 0.f;
#pragma unroll
    for (int i = 0; i < 16; ++i) {
      const float pw = proj_w[o * 256 + h * 16 + i];
#pragma unroll
      for (int j = 0; j < 8; ++j)
        s[j] += pw * attnw[((b * 8 + h) * 16 + i) * 16 + d0 + j];
    }
#pragma unroll
    for (int j = 0; j < 8; ++j) outv[j] = f2bf(s[j]);
  } else {
#pragma unroll
    for (int j = 0; j < 8; ++j) outv[j] = f2bf(proj_w[o * 256 + k0 + j]);
  }
  *(v8s*)(W2f + ((size_t)(b * 128 + g * 8 + ks) * 64 + lane) * 8) = outv;
}

// K4: out[m][o] = [v(m);x2(m)] @ W2[b]^T (M=131072,K=256,N=256). Fragment-major B pipeline.
__global__ __launch_bounds__(512, 4) void k4_out(const short* __restrict__ vbuf,
                                                 const float* __restrict__ x,
                                                 const short* __restrict__ W2f,
                                                 float* __restrict__ out) {
  __shared__ __align__(16) unsigned char sm[32768];
  const int tid = threadIdx.x;
  const size_t m0 = (size_t)blockIdx.x * 64;
  const int b = (int)(m0 >> 16);
  const int lane = tid & 63, wid = tid >> 6;
  const int wm = wid >> 2, wn = wid & 3;

  v8s pbB[3];
#pragma unroll
  for (int s = 0; s < 3; ++s) {
    const size_t off = ((size_t)(b * 128 + (0 * 4 + wn) * 8 + s) * 64 + lane) * 8;
    pbB[s] = *(const v8s*)(W2f + off);
  }
  {
    const int row = tid >> 3, c0 = (tid & 7) * 16;
    {
      const short* src = vbuf + (m0 + (size_t)row) * 128 + c0;
#pragma unroll
      for (int half = 0; half < 2; ++half) {
        const int col = c0 + half * 8;
        const int byo = (row * 512 + col * 2) ^ ((row & 7) << 4);
        *(v8s*)(sm + byo) = *(const v8s*)(src + half * 8);
      }
    }
    {
      const float* src = x + (m0 + (size_t)row) * 256 + 128 + c0;
#pragma unroll
      for (int half = 0; half < 2; ++half) {
        v4f f0 = *(const v4f*)(src + half * 8);
        v4f f1 = *(const v4f*)(src + half * 8 + 4);
        v4u hv;
        hv[0] = pack_rn(f0[0], f0[1]); hv[1] = pack_rn(f0[2], f0[3]);
        hv[2] = pack_rn(f1[0], f1[1]); hv[3] = pack_rn(f1[2], f1[3]);
        const int col = 128 + c0 + half * 8;
        const int byo = (row * 512 + col * 2) ^ ((row & 7) << 4);
        *(v4u*)(sm + byo) = hv;
      }
    }
  }
  __syncthreads();
  v8s af[8][2];
#pragma unroll
  for (int ks = 0; ks < 8; ++ks)
#pragma unroll
    for (int mi = 0; mi < 2; ++mi) {
      const int kb2 = (ks * 32 + ((lane >> 4) * 8)) * 2;
      const int m = wm * 32 + mi * 16 + (lane & 15);
      const int byoA = (m * 512 + kb2) ^ ((m & 7) << 4);
      af[ks][mi] = *(const v8s*)(sm + byoA);
    }
  const v4f vz = {0.f, 0.f, 0.f, 0.f};
  v4f acc[4][2];
#pragma unroll
  for (int i = 0; i < 4; ++i) { acc[i][0] = vz; acc[i][1] = vz; }
#pragma unroll
  for (int s = 0; s < 32; ++s) {
    const int nc = s >> 3, ks = s & 7, slot = s % 3;
    const v8s bf = pbB[slot];
    if (s + 3 < 32) {
      const int s3 = s + 3, nc3 = s3 >> 3, ks3 = s3 & 7;
      const size_t off = ((size_t)(b * 128 + (nc3 * 4 + wn) * 8 + ks3) * 64 + lane) * 8;
      pbB[slot] = *(const v8s*)(W2f + off);
    }
#pragma unroll
    for (int mi = 0; mi < 2; ++mi)
      acc[nc][mi] = mfma16(af[ks][mi], bf, acc[nc][mi]);
  }
#pragma unroll
  for (int nc = 0; nc < 4; ++nc)
#pragma unroll
    for (int mi = 0; mi < 2; ++mi)
#pragma unroll
      for (int r = 0; r < 4; ++r) {
        const int m = wm * 32 + mi * 16 + ((lane >> 4) * 4) + r;
        const int o = nc * 64 + wn * 16 + (lane & 15);
        out[(m0 + m) * 256 + o] = acc[nc][mi][r];
      }
}

extern "C" void kernel_launch(void* const* d_in, const int* in_sizes, int n_in,
                              void* d_out, int out_size, void* d_ws, size_t ws_size,
                              hipStream_t stream) {
  const float* x      = (const float*)d_in[0];
  const float* qkv_w  = (const float*)d_in[1];
  const float* dw_w   = (const float*)d_in[2];
  const float* proj_w = (const float*)d_in[3];
  const float* g1_w   = (const float*)d_in[4];
  const float* g1_b   = (const float*)d_in[5];
  const float* g2_w   = (const float*)d_in[6];
  const float* g2_b   = (const float*)d_in[7];
  const float* temp   = (const float*)d_in[8];
  const float* a1     = (const float*)d_in[9];
  const float* a2     = (const float*)d_in[10];
  const float* a3     = (const float*)d_in[11];
  const float* a4     = (const float*)d_in[12];
  float* out = (float*)d_out;
  char* ws = (char*)d_ws;

  double* gram  = (double*)(ws + OFF_GRAM);
  double* qn    = (double*)(ws + OFF_QN);
  double* kn    = (double*)(ws + OFF_KN);
  double* gsum  = (double*)(ws + OFF_GSUM);
  float*  attnw = (float*)(ws + OFF_ATTN);
  short*  wqh   = (short*)(ws + OFF_WQH);
  short*  wql   = (short*)(ws + OFF_WQL);
  short*  g1h   = (short*)(ws + OFF_G1H);
  short*  g1l   = (short*)(ws + OFF_G1L);
  short*  W2f   = (short*)(ws + OFF_W2);
  float*  qkf   = (float*)(ws + OFF_QK);
  short*  vb    = (short*)(ws + OFF_V);
  short*  vbuf  = (short*)(ws + OFF_VOUT);

  hipMemsetAsync(ws, 0, 40960, stream);                       // gram/qn/kn/gsum accumulators
  k0_split<<<40, 256, 0, stream>>>(qkv_w, g1_w, wqh, wql, g1h, g1l);
  k1f<<<2048, 512, 0, stream>>>(x, wqh, wql, g1h, g1l, g1_b, g2_w, g2_b, qkf, vb, gsum);
  k2_conv<<<dim3(256, 8, 2), 256, 0, stream>>>(qkf, vb, dw_w, gram, qn, kn, vbuf);
  k3a_attn<<<1, 256, 0, stream>>>(gram, qn, kn, gsum, temp, a1, a2, a3, a4, attnw);
  k3b_fold<<<dim3(16, 2), 512, 0, stream>>>(proj_w, attnw, W2f);
  k4_out<<<2048, 512, 0, stream>>>(vbuf, x, W2f, out);
  (void)in_sizes; (void)n_in; (void)out_size; (void)ws_size;
}